// Round 1
// baseline (542.456 us; speedup 1.0000x reference)
//
#include <hip/hip_runtime.h>
#include <hip/hip_bf16.h>

// Problem constants
#define BATCH 16
#define CH    32      // depthwise group count
#define CIN   64
#define OUTC  64
#define HH    128     // h after stride-2 stem
#define WW    128

// ---------------------------------------------------------------------------
// Kernel 0: transpose w_out [64][192] -> wT [192][64] for vectorized reads
// ---------------------------------------------------------------------------
__global__ __launch_bounds__(256) void k_transpose_wout(
    const float* __restrict__ w_out, float* __restrict__ wT) {
  int t = blockIdx.x * 256 + threadIdx.x;
  if (t < OUTC * 3 * CIN) {
    int o = t / (3 * CIN);
    int k = t % (3 * CIN);
    wT[k * OUTC + o] = w_out[t];
  }
}

// ---------------------------------------------------------------------------
// Kernel 1: stem = SiLU(conv3x3 stride2 pad1 (mas, w_inp) + b_inp)
// Output x -> ws  [B][CH][128][128] fp32
// Block: 256 threads, tile 8 rows x 32 cols of output pixels; each thread
// owns one pixel and all 32 output channels (acc[32]).
// ---------------------------------------------------------------------------
__global__ __launch_bounds__(256) void k_stem(
    const float* __restrict__ mas, const float* __restrict__ w_inp,
    const float* __restrict__ b_inp, float* __restrict__ xbuf) {
  __shared__ float xp[8][17][67];   // 8 in-ch chunk, 17 rows, 65 cols (pitch 67, odd)
  __shared__ float wl[8][9][32];    // [ci][tap][co] transposed weights

  const int bx = blockIdx.x;        // 0..3   (128/32 col tiles)
  const int by = blockIdx.y;        // 0..15  (128/8 row tiles)
  const int b  = blockIdx.z;        // batch
  const int t  = threadIdx.x;
  const int tx = t & 31;
  const int ty = t >> 5;

  const int I0 = by * 8, J0 = bx * 32;
  const int R0 = 2 * I0 - 1, C0 = 2 * J0 - 1;

  float acc[32];
#pragma unroll
  for (int i = 0; i < 32; ++i) acc[i] = 0.f;

  for (int cc = 0; cc < CH; cc += 8) {
    // stage transposed weights for this channel chunk
    for (int idx = t; idx < 8 * 9 * 32; idx += 256) {
      int co = idx & 31;
      int k  = (idx >> 5) % 9;
      int ci = idx / (9 * 32);
      wl[ci][k][co] = w_inp[(co * CH + (cc + ci)) * 9 + k];
    }
    // stage input patch (zero-filled at borders)
    for (int idx = t; idx < 8 * 17 * 65; idx += 256) {
      int c  = idx % 65;
      int r  = (idx / 65) % 17;
      int ci = idx / (65 * 17);
      int gr = R0 + r, gc = C0 + c;
      float v = 0.f;
      if (gr >= 0 && gr < 256 && gc >= 0 && gc < 256)
        v = mas[((b * CH + cc + ci) * 256 + gr) * 256 + gc];
      xp[ci][r][c] = v;
    }
    __syncthreads();

#pragma unroll
    for (int ci = 0; ci < 8; ++ci) {
#pragma unroll
      for (int ky = 0; ky < 3; ++ky) {
#pragma unroll
        for (int kx = 0; kx < 3; ++kx) {
          float v = xp[ci][2 * ty + ky][2 * tx + kx];
          const float* wp = &wl[ci][ky * 3 + kx][0];
#pragma unroll
          for (int q = 0; q < 8; ++q) {
            float4 w4 = *(const float4*)(wp + q * 4);
            acc[q * 4 + 0] += v * w4.x;
            acc[q * 4 + 1] += v * w4.y;
            acc[q * 4 + 2] += v * w4.z;
            acc[q * 4 + 3] += v * w4.w;
          }
        }
      }
    }
    __syncthreads();
  }

  const int i = I0 + ty, j = J0 + tx;
#pragma unroll
  for (int co = 0; co < 32; ++co) {
    float y = acc[co] + b_inp[co];
    float s = y / (1.f + __expf(-y));   // SiLU
    xbuf[((b * CH + co) * HH + i) * WW + j] = s;
  }
}

// ---------------------------------------------------------------------------
// Kernel 2: fused deltas + grouped 1x1 gates + concat + out conv (+bias)
// Block: 256 threads, 8x8 pixel tile. Phase 1 builds outs[192][64] in LDS
// (square 0..63, dout 64..127, cen 128..191). Phase 2: 64x64 register-blocked
// GEMM over K=192: out[o][p] = sum_k wT[k][o]*outs[k][p] + b_out[o].
// ---------------------------------------------------------------------------
__global__ __launch_bounds__(256) void k_fused(
    const float* __restrict__ xbuf, const float* __restrict__ cen,
    const float* __restrict__ w1, const float* __restrict__ w2,
    const float* __restrict__ w3, const float* __restrict__ wT,
    const float* __restrict__ b_out, float* __restrict__ out) {
  __shared__ float outs[192][64];      // 48 KiB
  __shared__ float xp[8][14][17];      // 8-ch chunk, 14x14 halo patch (pitch 17)
  __shared__ float wg[3][CH][2][8];    // w1,w2,w3

  const int bx = blockIdx.x;   // 0..15 (col tiles of 8)
  const int by = blockIdx.y;   // 0..15 (row tiles of 8)
  const int b  = blockIdx.z;
  const int t  = threadIdx.x;
  const int I0 = by * 8, J0 = bx * 8;

  // stage gating weights (flat layouts match)
  {
    float* wgf = &wg[0][0][0][0];
    for (int idx = t; idx < 3 * 512; idx += 256) {
      float v;
      if (idx < 512)       v = w1[idx];
      else if (idx < 1024) v = w2[idx - 512];
      else                 v = w3[idx - 1024];
      wgf[idx] = v;
    }
  }
  // stage cen into outs rows 128..191
  for (int idx = t; idx < 64 * 64; idx += 256) {
    int ccn = idx >> 6;
    int p   = idx & 63;
    int py = p >> 3, px = p & 7;
    outs[128 + ccn][p] = cen[((b * CIN + ccn) * HH + I0 + py) * WW + J0 + px];
  }

  // channel chunks of 8: deltas + gates -> outs rows [0..127]
  for (int cg = 0; cg < CH; cg += 8) {
    for (int idx = t; idx < 8 * 14 * 14; idx += 256) {
      int cc = idx % 14;
      int r  = (idx / 14) % 14;
      int c  = idx / 196;
      int gi = I0 - 3 + r, gj = J0 - 3 + cc;
      float v = 0.f;
      if (gi >= 0 && gi < HH && gj >= 0 && gj < WW)
        v = xbuf[((b * CH + cg + c) * HH + gi) * WW + gj];
      xp[c][r][cc] = v;
    }
    __syncthreads();

    for (int task = t; task < 512; task += 256) {
      int c = task >> 6;
      int p = task & 63;
      int py = p >> 3, px = p & 7;
      float xc = xp[c][py + 3][px + 3];
      float d[8];
      d[0] = xc - xp[c][py + 0][px + 0];  // (-3,-3)
      d[1] = xc - xp[c][py + 0][px + 3];  // (-3, 0)
      d[2] = xc - xp[c][py + 0][px + 6];  // (-3, 3)
      d[3] = xc - xp[c][py + 3][px + 6];  // ( 0, 3)
      d[4] = xc - xp[c][py + 6][px + 6];  // ( 3, 3)
      d[5] = xc - xp[c][py + 6][px + 3];  // ( 3, 0)
      d[6] = xc - xp[c][py + 6][px + 0];  // ( 3,-3)
      d[7] = xc - xp[c][py + 3][px + 0];  // ( 0,-3)
      const int C = cg + c;
      float g10 = 0, g11 = 0, g20 = 0, g21 = 0, g30 = 0, g31 = 0;
#pragma unroll
      for (int k = 0; k < 8; ++k) {
        g10 += d[k] * wg[0][C][0][k];
        g11 += d[k] * wg[0][C][1][k];
        g20 += d[k] * wg[1][C][0][k];
        g21 += d[k] * wg[1][C][1][k];
        g30 += d[k] * wg[2][C][0][k];
        g31 += d[k] * wg[2][C][1][k];
      }
      outs[2 * C + 0][p]      = g10 * g20;   // square
      outs[2 * C + 1][p]      = g11 * g21;
      outs[64 + 2 * C + 0][p] = g30;         // dout
      outs[64 + 2 * C + 1][p] = g31;
    }
    __syncthreads();
  }

  // Phase 2: 64(o) x 64(p) GEMM, 4x4 micro-tile per thread, K=192
  const int og = t >> 4, pg = t & 15;
  const int o0 = og * 4, p0 = pg * 4;
  float acc[4][4];
#pragma unroll
  for (int i = 0; i < 4; ++i)
#pragma unroll
    for (int j = 0; j < 4; ++j) acc[i][j] = 0.f;

#pragma unroll 4
  for (int k = 0; k < 192; ++k) {
    float4 w4 = *(const float4*)(wT + k * OUTC + o0);
    float4 a4 = *(const float4*)(&outs[k][p0]);
    acc[0][0] += w4.x * a4.x; acc[0][1] += w4.x * a4.y;
    acc[0][2] += w4.x * a4.z; acc[0][3] += w4.x * a4.w;
    acc[1][0] += w4.y * a4.x; acc[1][1] += w4.y * a4.y;
    acc[1][2] += w4.y * a4.z; acc[1][3] += w4.y * a4.w;
    acc[2][0] += w4.z * a4.x; acc[2][1] += w4.z * a4.y;
    acc[2][2] += w4.z * a4.z; acc[2][3] += w4.z * a4.w;
    acc[3][0] += w4.w * a4.x; acc[3][1] += w4.w * a4.y;
    acc[3][2] += w4.w * a4.z; acc[3][3] += w4.w * a4.w;
  }

  const int py = p0 >> 3, px = p0 & 7;   // p0 in {0,4,...,60}: 4 pixels same row
#pragma unroll
  for (int i = 0; i < 4; ++i) {
    float bo = b_out[o0 + i];
    float4 r;
    r.x = acc[i][0] + bo;
    r.y = acc[i][1] + bo;
    r.z = acc[i][2] + bo;
    r.w = acc[i][3] + bo;
    *(float4*)(&out[((b * OUTC + o0 + i) * HH + I0 + py) * WW + J0 + px]) = r;
  }
}

// ---------------------------------------------------------------------------
extern "C" void kernel_launch(void* const* d_in, const int* in_sizes, int n_in,
                              void* d_out, int out_size, void* d_ws, size_t ws_size,
                              hipStream_t stream) {
  const float* cen   = (const float*)d_in[0];
  const float* mas   = (const float*)d_in[1];
  const float* w_inp = (const float*)d_in[2];
  const float* b_inp = (const float*)d_in[3];
  const float* w1    = (const float*)d_in[4];
  const float* w2    = (const float*)d_in[5];
  const float* w3    = (const float*)d_in[6];
  const float* w_out = (const float*)d_in[7];
  const float* b_out = (const float*)d_in[8];
  float* out = (float*)d_out;

  float* xbuf = (float*)d_ws;                        // 16*32*128*128 fp32 = 33.5 MB
  float* wT   = xbuf + (size_t)BATCH * CH * HH * WW; // 192*64 fp32

  hipLaunchKernelGGL(k_transpose_wout, dim3(48), dim3(256), 0, stream, w_out, wT);
  hipLaunchKernelGGL(k_stem, dim3(4, 16, 16), dim3(256), 0, stream,
                     mas, w_inp, b_inp, xbuf);
  hipLaunchKernelGGL(k_fused, dim3(16, 16, 16), dim3(256), 0, stream,
                     xbuf, cen, w1, w2, w3, wT, b_out, out);
}

// Round 2
// 363.762 us; speedup vs baseline: 1.4912x; 1.4912x over previous
//
#include <hip/hip_runtime.h>
#include <hip/hip_bf16.h>

// Problem constants
#define BATCH 16
#define CH    32      // depthwise group count
#define CIN   64
#define OUTC  64
#define HH    128     // h after stride-2 stem
#define WW    128

// ---------------------------------------------------------------------------
// Kernel 0: transpose w_out [64][192] -> wT [192][64] for vectorized reads
// ---------------------------------------------------------------------------
__global__ __launch_bounds__(256) void k_transpose_wout(
    const float* __restrict__ w_out, float* __restrict__ wT) {
  int t = blockIdx.x * 256 + threadIdx.x;
  if (t < OUTC * 3 * CIN) {
    int o = t / (3 * CIN);
    int k = t % (3 * CIN);
    wT[k * OUTC + o] = w_out[t];
  }
}

// ---------------------------------------------------------------------------
// Kernel 1: stem = SiLU(conv3x3 stride2 pad1 (mas, w_inp) + b_inp)
// Tile: 16 rows x 32 cols of output; 256 threads; each thread owns 2 pixels
// (rows ty and ty+8) and all 32 output channels. ci processed in chunks of 4.
// Each broadcast weight float4 feeds 8 FMAs (2 px x 4 co) -> LDS-issue no
// longer dominates VALU.
// ---------------------------------------------------------------------------
__global__ __launch_bounds__(256) void k_stem(
    const float* __restrict__ mas, const float* __restrict__ w_inp,
    const float* __restrict__ b_inp, float* __restrict__ xbuf) {
  __shared__ float xp[4][33][67];   // 4 in-ch, 33 rows, 65 cols used (pitch 67)
  __shared__ float wl[4][9][32];    // [ci][tap][co]

  const int bx = blockIdx.x;        // 0..3   (128/32 col tiles)
  const int by = blockIdx.y;        // 0..7   (128/16 row tiles)
  const int b  = blockIdx.z;        // batch
  const int t  = threadIdx.x;
  const int tx = t & 31;
  const int ty = t >> 5;            // 0..7

  const int I0 = by * 16, J0 = bx * 32;
  const int R0 = 2 * I0 - 1, C0 = 2 * J0 - 1;

  float acc[2][32];
#pragma unroll
  for (int r = 0; r < 2; ++r)
#pragma unroll
    for (int i = 0; i < 32; ++i) acc[r][i] = 0.f;

  for (int cc = 0; cc < CH; cc += 4) {
    // stage transposed weights for this channel chunk
    for (int idx = t; idx < 4 * 9 * 32; idx += 256) {
      int co = idx & 31;
      int k  = (idx >> 5) % 9;
      int ci = idx / (9 * 32);
      wl[ci][k][co] = w_inp[(co * CH + (cc + ci)) * 9 + k];
    }
    // stage input patch (zero-filled at borders): 4 x 33 x 65
    for (int idx = t; idx < 4 * 33 * 65; idx += 256) {
      int c  = idx % 65;
      int r  = (idx / 65) % 33;
      int ci = idx / (65 * 33);
      int gr = R0 + r, gc = C0 + c;
      float v = 0.f;
      if (gr >= 0 && gr < 256 && gc >= 0 && gc < 256)
        v = mas[((b * CH + cc + ci) * 256 + gr) * 256 + gc];
      xp[ci][r][c] = v;
    }
    __syncthreads();

#pragma unroll
    for (int ci = 0; ci < 4; ++ci) {
#pragma unroll
      for (int ky = 0; ky < 3; ++ky) {
#pragma unroll
        for (int kx = 0; kx < 3; ++kx) {
          float v0 = xp[ci][2 * ty + ky][2 * tx + kx];
          float v1 = xp[ci][2 * ty + 16 + ky][2 * tx + kx];
          const float* wp = &wl[ci][ky * 3 + kx][0];
#pragma unroll
          for (int q = 0; q < 8; ++q) {
            float4 w4 = *(const float4*)(wp + q * 4);
            acc[0][q * 4 + 0] += v0 * w4.x;
            acc[0][q * 4 + 1] += v0 * w4.y;
            acc[0][q * 4 + 2] += v0 * w4.z;
            acc[0][q * 4 + 3] += v0 * w4.w;
            acc[1][q * 4 + 0] += v1 * w4.x;
            acc[1][q * 4 + 1] += v1 * w4.y;
            acc[1][q * 4 + 2] += v1 * w4.z;
            acc[1][q * 4 + 3] += v1 * w4.w;
          }
        }
      }
    }
    __syncthreads();
  }

#pragma unroll
  for (int r = 0; r < 2; ++r) {
    const int i = I0 + ty + r * 8, j = J0 + tx;
#pragma unroll
    for (int co = 0; co < 32; ++co) {
      float y = acc[r][co] + b_inp[co];
      float s = y / (1.f + __expf(-y));   // SiLU
      xbuf[((b * CH + co) * HH + i) * WW + j] = s;
    }
  }
}

// ---------------------------------------------------------------------------
// Kernel 2: fused deltas + grouped 1x1 gates + concat + out conv (+bias)
// 256 threads, 8x8 pixel tile. K-chunked: 32 k-rows at a time go through an
// 8 KiB LDS dchunk with the matching wT rows in an 8 KiB wchunk; the 4x4
// micro-tile GEMM accumulates per chunk. No global loads in the inner loop;
// total LDS ~30 KiB -> 4-5 blocks/CU.
// ---------------------------------------------------------------------------
__global__ __launch_bounds__(256) void k_fused(
    const float* __restrict__ xbuf, const float* __restrict__ cen,
    const float* __restrict__ w1, const float* __restrict__ w2,
    const float* __restrict__ w3, const float* __restrict__ wT,
    const float* __restrict__ b_out, float* __restrict__ out) {
  __shared__ float xp[8][14][17];      // 8-ch chunk, 14x14 halo patch (pitch 17)
  __shared__ float wg[3][CH][2][8];    // w1,w2,w3
  __shared__ float dchunk[32][64];     // 32 k-rows x 64 pixels
  __shared__ float wchunk[32][64];     // matching wT rows

  const int bx = blockIdx.x;   // 0..15 (col tiles of 8)
  const int by = blockIdx.y;   // 0..15 (row tiles of 8)
  const int b  = blockIdx.z;
  const int t  = threadIdx.x;
  const int I0 = by * 8, J0 = bx * 8;

  // stage gating weights (flat layouts match)
  {
    float* wgf = &wg[0][0][0][0];
    for (int idx = t; idx < 3 * 512; idx += 256) {
      float v;
      if (idx < 512)       v = w1[idx];
      else if (idx < 1024) v = w2[idx - 512];
      else                 v = w3[idx - 1024];
      wgf[idx] = v;
    }
  }

  const int og = t >> 4, pg = t & 15;
  const int o0 = og * 4, p0 = pg * 4;
  float acc[4][4];
#pragma unroll
  for (int i = 0; i < 4; ++i)
#pragma unroll
    for (int j = 0; j < 4; ++j) acc[i][j] = 0.f;

  const int wk = t >> 3;           // wchunk staging: row this thread fills
  const int wo = (t & 7) * 8;      // 8 floats starting here

  // ---- channel chunks: deltas + gates -> dchunk rows, GEMM accumulate ----
  for (int cg = 0; cg < CH; cg += 8) {
    // stage halo patch
    for (int idx = t; idx < 8 * 14 * 14; idx += 256) {
      int cc2 = idx % 14;
      int r   = (idx / 14) % 14;
      int c   = idx / 196;
      int gi = I0 - 3 + r, gj = J0 - 3 + cc2;
      float v = 0.f;
      if (gi >= 0 && gi < HH && gj >= 0 && gj < WW)
        v = xbuf[((b * CH + cg + c) * HH + gi) * WW + gj];
      xp[c][r][cc2] = v;
    }
    // stage wT chunk: local rows 0..15 -> square rows 2cg..2cg+15,
    //                 local rows 16..31 -> dout rows 64+2cg..64+2cg+15
    {
      int gk = (wk < 16) ? (2 * cg + wk) : (64 + 2 * cg + wk - 16);
      float4 a = *(const float4*)(wT + gk * OUTC + wo);
      float4 b4 = *(const float4*)(wT + gk * OUTC + wo + 4);
      *(float4*)(&wchunk[wk][wo]) = a;
      *(float4*)(&wchunk[wk][wo + 4]) = b4;
    }
    __syncthreads();

    // deltas + gates -> dchunk (local rows: sq 2c+{0,1}, dout 16+2c+{0,1})
    for (int task = t; task < 512; task += 256) {
      int c = task >> 6;
      int p = task & 63;
      int py = p >> 3, px = p & 7;
      float xc = xp[c][py + 3][px + 3];
      float d[8];
      d[0] = xc - xp[c][py + 0][px + 0];  // (-3,-3)
      d[1] = xc - xp[c][py + 0][px + 3];  // (-3, 0)
      d[2] = xc - xp[c][py + 0][px + 6];  // (-3, 3)
      d[3] = xc - xp[c][py + 3][px + 6];  // ( 0, 3)
      d[4] = xc - xp[c][py + 6][px + 6];  // ( 3, 3)
      d[5] = xc - xp[c][py + 6][px + 3];  // ( 3, 0)
      d[6] = xc - xp[c][py + 6][px + 0];  // ( 3,-3)
      d[7] = xc - xp[c][py + 3][px + 0];  // ( 0,-3)
      const int C = cg + c;
      float g10 = 0, g11 = 0, g20 = 0, g21 = 0, g30 = 0, g31 = 0;
#pragma unroll
      for (int k = 0; k < 8; ++k) {
        g10 += d[k] * wg[0][C][0][k];
        g11 += d[k] * wg[0][C][1][k];
        g20 += d[k] * wg[1][C][0][k];
        g21 += d[k] * wg[1][C][1][k];
        g30 += d[k] * wg[2][C][0][k];
        g31 += d[k] * wg[2][C][1][k];
      }
      dchunk[2 * c + 0][p]      = g10 * g20;   // square
      dchunk[2 * c + 1][p]      = g11 * g21;
      dchunk[16 + 2 * c + 0][p] = g30;         // dout
      dchunk[16 + 2 * c + 1][p] = g31;
    }
    __syncthreads();

    // GEMM accumulate over this chunk's 32 k-rows
#pragma unroll 4
    for (int k = 0; k < 32; ++k) {
      float4 w4 = *(const float4*)(&wchunk[k][o0]);
      float4 a4 = *(const float4*)(&dchunk[k][p0]);
      acc[0][0] += w4.x * a4.x; acc[0][1] += w4.x * a4.y;
      acc[0][2] += w4.x * a4.z; acc[0][3] += w4.x * a4.w;
      acc[1][0] += w4.y * a4.x; acc[1][1] += w4.y * a4.y;
      acc[1][2] += w4.y * a4.z; acc[1][3] += w4.y * a4.w;
      acc[2][0] += w4.z * a4.x; acc[2][1] += w4.z * a4.y;
      acc[2][2] += w4.z * a4.z; acc[2][3] += w4.z * a4.w;
      acc[3][0] += w4.w * a4.x; acc[3][1] += w4.w * a4.y;
      acc[3][2] += w4.w * a4.z; acc[3][3] += w4.w * a4.w;
    }
    __syncthreads();
  }

  // ---- cen chunks: rows 128..191 of the outs panel ----
  for (int cc = 0; cc < 2; ++cc) {
    {
      int gk = 128 + cc * 32 + wk;
      float4 a = *(const float4*)(wT + gk * OUTC + wo);
      float4 b4 = *(const float4*)(wT + gk * OUTC + wo + 4);
      *(float4*)(&wchunk[wk][wo]) = a;
      *(float4*)(&wchunk[wk][wo + 4]) = b4;
    }
    for (int idx = t; idx < 2048; idx += 256) {
      int k = idx >> 6;
      int p = idx & 63;
      int py = p >> 3, px = p & 7;
      dchunk[k][p] =
          cen[((b * CIN + cc * 32 + k) * HH + I0 + py) * WW + J0 + px];
    }
    __syncthreads();

#pragma unroll 4
    for (int k = 0; k < 32; ++k) {
      float4 w4 = *(const float4*)(&wchunk[k][o0]);
      float4 a4 = *(const float4*)(&dchunk[k][p0]);
      acc[0][0] += w4.x * a4.x; acc[0][1] += w4.x * a4.y;
      acc[0][2] += w4.x * a4.z; acc[0][3] += w4.x * a4.w;
      acc[1][0] += w4.y * a4.x; acc[1][1] += w4.y * a4.y;
      acc[1][2] += w4.y * a4.z; acc[1][3] += w4.y * a4.w;
      acc[2][0] += w4.z * a4.x; acc[2][1] += w4.z * a4.y;
      acc[2][2] += w4.z * a4.z; acc[2][3] += w4.z * a4.w;
      acc[3][0] += w4.w * a4.x; acc[3][1] += w4.w * a4.y;
      acc[3][2] += w4.w * a4.z; acc[3][3] += w4.w * a4.w;
    }
    __syncthreads();
  }

  // epilogue: p0 in {0,4,...,60} -> 4 pixels in one row
  const int py = p0 >> 3, px = p0 & 7;
#pragma unroll
  for (int i = 0; i < 4; ++i) {
    float bo = b_out[o0 + i];
    float4 r;
    r.x = acc[i][0] + bo;
    r.y = acc[i][1] + bo;
    r.z = acc[i][2] + bo;
    r.w = acc[i][3] + bo;
    *(float4*)(&out[((b * OUTC + o0 + i) * HH + I0 + py) * WW + J0 + px]) = r;
  }
}

// ---------------------------------------------------------------------------
extern "C" void kernel_launch(void* const* d_in, const int* in_sizes, int n_in,
                              void* d_out, int out_size, void* d_ws, size_t ws_size,
                              hipStream_t stream) {
  const float* cen   = (const float*)d_in[0];
  const float* mas   = (const float*)d_in[1];
  const float* w_inp = (const float*)d_in[2];
  const float* b_inp = (const float*)d_in[3];
  const float* w1    = (const float*)d_in[4];
  const float* w2    = (const float*)d_in[5];
  const float* w3    = (const float*)d_in[6];
  const float* w_out = (const float*)d_in[7];
  const float* b_out = (const float*)d_in[8];
  float* out = (float*)d_out;

  float* xbuf = (float*)d_ws;                        // 16*32*128*128 fp32 = 33.5 MB
  float* wT   = xbuf + (size_t)BATCH * CH * HH * WW; // 192*64 fp32

  hipLaunchKernelGGL(k_transpose_wout, dim3(48), dim3(256), 0, stream, w_out, wT);
  hipLaunchKernelGGL(k_stem, dim3(4, 8, 16), dim3(256), 0, stream,
                     mas, w_inp, b_inp, xbuf);
  hipLaunchKernelGGL(k_fused, dim3(16, 16, 16), dim3(256), 0, stream,
                     xbuf, cen, w1, w2, w3, wT, b_out, out);
}

// Round 3
// 346.291 us; speedup vs baseline: 1.5665x; 1.0505x over previous
//
#include <hip/hip_runtime.h>
#include <hip/hip_bf16.h>

// Problem constants
#define BATCH 16
#define CH    32      // depthwise group count
#define CIN   64
#define OUTC  64
#define HH    128     // h after stride-2 stem
#define WW    128

// ---------------------------------------------------------------------------
// Kernel 0: weight prep.
//  - wT  [192][64]: transpose of w_out [64][192]
//  - wTs [32][9][32]: stem weights w_inp [co][ci][tap] -> [ci][tap][co]
// ---------------------------------------------------------------------------
__global__ __launch_bounds__(256) void k_prep_weights(
    const float* __restrict__ w_out, const float* __restrict__ w_inp,
    float* __restrict__ wT, float* __restrict__ wTs) {
  int t = blockIdx.x * 256 + threadIdx.x;
  if (t < OUTC * 3 * CIN) {
    int o = t / (3 * CIN);
    int k = t % (3 * CIN);
    wT[k * OUTC + o] = w_out[t];
  }
  int t2 = t - OUTC * 3 * CIN;
  if (t2 >= 0 && t2 < CH * 9 * CH) {
    // t2 indexes [co][ci][tap] flat (source order)
    int tap = t2 % 9;
    int ci  = (t2 / 9) % CH;
    int co  = t2 / (9 * CH);
    wTs[(ci * 9 + tap) * CH + co] = w_inp[t2];
  }
}

// ---------------------------------------------------------------------------
// Kernel 1: stem = SiLU(conv3x3 stride2 pad1 (mas, w_inp) + b_inp)
// Tile: 8 out rows x 64 out cols. 256 threads = 4 waves; wave g owns output
// channels [8g, 8g+8). Lane tx owns one output column, all 8 rows.
// Weights are wave-uniform -> scalar loads (no LDS, no VALU issue).
// Inputs staged in LDS per 4-ci chunk; each ds_read_b32 feeds 8 FMAs.
// ---------------------------------------------------------------------------
__global__ __launch_bounds__(256) void k_stem(
    const float* __restrict__ mas, const float* __restrict__ wTs,
    const float* __restrict__ b_inp, float* __restrict__ xbuf) {
  __shared__ float xp[4][17][129];   // 4 in-ch, 17 input rows, 129 input cols

  const int bx = blockIdx.x;        // 0..1   (128/64 col tiles)
  const int by = blockIdx.y;        // 0..15  (128/8 row tiles)
  const int b  = blockIdx.z;        // batch
  const int t  = threadIdx.x;
  const int tx = t & 63;
  int gco = (t >> 6) << 3;          // wave-uniform base output channel
  gco = __builtin_amdgcn_readfirstlane(gco);

  const int I0 = by * 8, J0 = bx * 64;
  const int R0 = 2 * I0 - 1, C0 = 2 * J0 - 1;

  float acc[8][8];                  // [row][co]
#pragma unroll
  for (int r = 0; r < 8; ++r)
#pragma unroll
    for (int j = 0; j < 8; ++j) acc[r][j] = 0.f;

  for (int cc = 0; cc < CH; cc += 4) {
    // stage input patch (zero-filled at borders): 4 x 17 x 129
    for (int idx = t; idx < 4 * 17 * 129; idx += 256) {
      int c  = idx % 129;
      int r  = (idx / 129) % 17;
      int ci = idx / (129 * 17);
      int gr = R0 + r, gc = C0 + c;
      float v = 0.f;
      // gr <= 255 always (by<=15 -> R0+16 <= 255); check gr>=0 and cols
      if (gr >= 0 && gc >= 0 && gc < 256)
        v = mas[((b * CH + cc + ci) * 256 + gr) * 256 + gc];
      xp[ci][r][c] = v;
    }
    __syncthreads();

#pragma unroll
    for (int ci = 0; ci < 4; ++ci) {
      const float* wbase = wTs + (cc + ci) * 9 * CH + gco;
#pragma unroll
      for (int ky = 0; ky < 3; ++ky) {
#pragma unroll
        for (int kx = 0; kx < 3; ++kx) {
          float4 wa = *(const float4*)(wbase + (ky * 3 + kx) * CH);
          float4 wb = *(const float4*)(wbase + (ky * 3 + kx) * CH + 4);
          float v[8];
#pragma unroll
          for (int r = 0; r < 8; ++r)
            v[r] = xp[ci][2 * r + ky][2 * tx + kx];
#pragma unroll
          for (int r = 0; r < 8; ++r) {
            acc[r][0] += v[r] * wa.x;
            acc[r][1] += v[r] * wa.y;
            acc[r][2] += v[r] * wa.z;
            acc[r][3] += v[r] * wa.w;
            acc[r][4] += v[r] * wb.x;
            acc[r][5] += v[r] * wb.y;
            acc[r][6] += v[r] * wb.z;
            acc[r][7] += v[r] * wb.w;
          }
        }
      }
    }
    __syncthreads();
  }

  // epilogue: bias + SiLU + coalesced stores (lanes cover a full row)
#pragma unroll
  for (int j = 0; j < 8; ++j) {
    float bj = b_inp[gco + j];
#pragma unroll
    for (int r = 0; r < 8; ++r) {
      float y = acc[r][j] + bj;
      float s = y / (1.f + __expf(-y));   // SiLU
      xbuf[((b * CH + gco + j) * HH + I0 + r) * WW + J0 + tx] = s;
    }
  }
}

// ---------------------------------------------------------------------------
// Kernel 2: fused deltas + grouped 1x1 gates + concat + out conv (+bias)
// (unchanged from round 1)
// ---------------------------------------------------------------------------
__global__ __launch_bounds__(256) void k_fused(
    const float* __restrict__ xbuf, const float* __restrict__ cen,
    const float* __restrict__ w1, const float* __restrict__ w2,
    const float* __restrict__ w3, const float* __restrict__ wT,
    const float* __restrict__ b_out, float* __restrict__ out) {
  __shared__ float xp[8][14][17];      // 8-ch chunk, 14x14 halo patch (pitch 17)
  __shared__ float wg[3][CH][2][8];    // w1,w2,w3
  __shared__ float dchunk[32][64];     // 32 k-rows x 64 pixels
  __shared__ float wchunk[32][64];     // matching wT rows

  const int bx = blockIdx.x;   // 0..15 (col tiles of 8)
  const int by = blockIdx.y;   // 0..15 (row tiles of 8)
  const int b  = blockIdx.z;
  const int t  = threadIdx.x;
  const int I0 = by * 8, J0 = bx * 8;

  // stage gating weights (flat layouts match)
  {
    float* wgf = &wg[0][0][0][0];
    for (int idx = t; idx < 3 * 512; idx += 256) {
      float v;
      if (idx < 512)       v = w1[idx];
      else if (idx < 1024) v = w2[idx - 512];
      else                 v = w3[idx - 1024];
      wgf[idx] = v;
    }
  }

  const int og = t >> 4, pg = t & 15;
  const int o0 = og * 4, p0 = pg * 4;
  float acc[4][4];
#pragma unroll
  for (int i = 0; i < 4; ++i)
#pragma unroll
    for (int j = 0; j < 4; ++j) acc[i][j] = 0.f;

  const int wk = t >> 3;           // wchunk staging: row this thread fills
  const int wo = (t & 7) * 8;      // 8 floats starting here

  // ---- channel chunks: deltas + gates -> dchunk rows, GEMM accumulate ----
  for (int cg = 0; cg < CH; cg += 8) {
    // stage halo patch
    for (int idx = t; idx < 8 * 14 * 14; idx += 256) {
      int cc2 = idx % 14;
      int r   = (idx / 14) % 14;
      int c   = idx / 196;
      int gi = I0 - 3 + r, gj = J0 - 3 + cc2;
      float v = 0.f;
      if (gi >= 0 && gi < HH && gj >= 0 && gj < WW)
        v = xbuf[((b * CH + cg + c) * HH + gi) * WW + gj];
      xp[c][r][cc2] = v;
    }
    // stage wT chunk: local rows 0..15 -> square rows 2cg..2cg+15,
    //                 local rows 16..31 -> dout rows 64+2cg..64+2cg+15
    {
      int gk = (wk < 16) ? (2 * cg + wk) : (64 + 2 * cg + wk - 16);
      float4 a = *(const float4*)(wT + gk * OUTC + wo);
      float4 b4 = *(const float4*)(wT + gk * OUTC + wo + 4);
      *(float4*)(&wchunk[wk][wo]) = a;
      *(float4*)(&wchunk[wk][wo + 4]) = b4;
    }
    __syncthreads();

    // deltas + gates -> dchunk (local rows: sq 2c+{0,1}, dout 16+2c+{0,1})
    for (int task = t; task < 512; task += 256) {
      int c = task >> 6;
      int p = task & 63;
      int py = p >> 3, px = p & 7;
      float xc = xp[c][py + 3][px + 3];
      float d[8];
      d[0] = xc - xp[c][py + 0][px + 0];  // (-3,-3)
      d[1] = xc - xp[c][py + 0][px + 3];  // (-3, 0)
      d[2] = xc - xp[c][py + 0][px + 6];  // (-3, 3)
      d[3] = xc - xp[c][py + 3][px + 6];  // ( 0, 3)
      d[4] = xc - xp[c][py + 6][px + 6];  // ( 3, 3)
      d[5] = xc - xp[c][py + 6][px + 3];  // ( 3, 0)
      d[6] = xc - xp[c][py + 6][px + 0];  // ( 3,-3)
      d[7] = xc - xp[c][py + 3][px + 0];  // ( 0,-3)
      const int C = cg + c;
      float g10 = 0, g11 = 0, g20 = 0, g21 = 0, g30 = 0, g31 = 0;
#pragma unroll
      for (int k = 0; k < 8; ++k) {
        g10 += d[k] * wg[0][C][0][k];
        g11 += d[k] * wg[0][C][1][k];
        g20 += d[k] * wg[1][C][0][k];
        g21 += d[k] * wg[1][C][1][k];
        g30 += d[k] * wg[2][C][0][k];
        g31 += d[k] * wg[2][C][1][k];
      }
      dchunk[2 * c + 0][p]      = g10 * g20;   // square
      dchunk[2 * c + 1][p]      = g11 * g21;
      dchunk[16 + 2 * c + 0][p] = g30;         // dout
      dchunk[16 + 2 * c + 1][p] = g31;
    }
    __syncthreads();

    // GEMM accumulate over this chunk's 32 k-rows
#pragma unroll 4
    for (int k = 0; k < 32; ++k) {
      float4 w4 = *(const float4*)(&wchunk[k][o0]);
      float4 a4 = *(const float4*)(&dchunk[k][p0]);
      acc[0][0] += w4.x * a4.x; acc[0][1] += w4.x * a4.y;
      acc[0][2] += w4.x * a4.z; acc[0][3] += w4.x * a4.w;
      acc[1][0] += w4.y * a4.x; acc[1][1] += w4.y * a4.y;
      acc[1][2] += w4.y * a4.z; acc[1][3] += w4.y * a4.w;
      acc[2][0] += w4.z * a4.x; acc[2][1] += w4.z * a4.y;
      acc[2][2] += w4.z * a4.z; acc[2][3] += w4.z * a4.w;
      acc[3][0] += w4.w * a4.x; acc[3][1] += w4.w * a4.y;
      acc[3][2] += w4.w * a4.z; acc[3][3] += w4.w * a4.w;
    }
    __syncthreads();
  }

  // ---- cen chunks: rows 128..191 of the outs panel ----
  for (int cc = 0; cc < 2; ++cc) {
    {
      int gk = 128 + cc * 32 + wk;
      float4 a = *(const float4*)(wT + gk * OUTC + wo);
      float4 b4 = *(const float4*)(wT + gk * OUTC + wo + 4);
      *(float4*)(&wchunk[wk][wo]) = a;
      *(float4*)(&wchunk[wk][wo + 4]) = b4;
    }
    for (int idx = t; idx < 2048; idx += 256) {
      int k = idx >> 6;
      int p = idx & 63;
      int py = p >> 3, px = p & 7;
      dchunk[k][p] =
          cen[((b * CIN + cc * 32 + k) * HH + I0 + py) * WW + J0 + px];
    }
    __syncthreads();

#pragma unroll 4
    for (int k = 0; k < 32; ++k) {
      float4 w4 = *(const float4*)(&wchunk[k][o0]);
      float4 a4 = *(const float4*)(&dchunk[k][p0]);
      acc[0][0] += w4.x * a4.x; acc[0][1] += w4.x * a4.y;
      acc[0][2] += w4.x * a4.z; acc[0][3] += w4.x * a4.w;
      acc[1][0] += w4.y * a4.x; acc[1][1] += w4.y * a4.y;
      acc[1][2] += w4.y * a4.z; acc[1][3] += w4.y * a4.w;
      acc[2][0] += w4.z * a4.x; acc[2][1] += w4.z * a4.y;
      acc[2][2] += w4.z * a4.z; acc[2][3] += w4.z * a4.w;
      acc[3][0] += w4.w * a4.x; acc[3][1] += w4.w * a4.y;
      acc[3][2] += w4.w * a4.z; acc[3][3] += w4.w * a4.w;
    }
    __syncthreads();
  }

  // epilogue: p0 in {0,4,...,60} -> 4 pixels in one row
  const int py = p0 >> 3, px = p0 & 7;
#pragma unroll
  for (int i = 0; i < 4; ++i) {
    float bo = b_out[o0 + i];
    float4 r;
    r.x = acc[i][0] + bo;
    r.y = acc[i][1] + bo;
    r.z = acc[i][2] + bo;
    r.w = acc[i][3] + bo;
    *(float4*)(&out[((b * OUTC + o0 + i) * HH + I0 + py) * WW + J0 + px]) = r;
  }
}

// ---------------------------------------------------------------------------
extern "C" void kernel_launch(void* const* d_in, const int* in_sizes, int n_in,
                              void* d_out, int out_size, void* d_ws, size_t ws_size,
                              hipStream_t stream) {
  const float* cen   = (const float*)d_in[0];
  const float* mas   = (const float*)d_in[1];
  const float* w_inp = (const float*)d_in[2];
  const float* b_inp = (const float*)d_in[3];
  const float* w1    = (const float*)d_in[4];
  const float* w2    = (const float*)d_in[5];
  const float* w3    = (const float*)d_in[6];
  const float* w_out = (const float*)d_in[7];
  const float* b_out = (const float*)d_in[8];
  float* out = (float*)d_out;

  float* xbuf = (float*)d_ws;                        // 16*32*128*128 fp32 = 33.5 MB
  float* wT   = xbuf + (size_t)BATCH * CH * HH * WW; // 192*64 fp32
  float* wTs  = wT + 192 * OUTC;                     // 32*9*32 fp32

  hipLaunchKernelGGL(k_prep_weights, dim3(84), dim3(256), 0, stream,
                     w_out, w_inp, wT, wTs);
  hipLaunchKernelGGL(k_stem, dim3(2, 16, 16), dim3(256), 0, stream,
                     mas, wTs, b_inp, xbuf);
  hipLaunchKernelGGL(k_fused, dim3(16, 16, 16), dim3(256), 0, stream,
                     xbuf, cen, w1, w2, w3, wT, b_out, out);
}

// Round 4
// 285.633 us; speedup vs baseline: 1.8991x; 1.2124x over previous
//
#include <hip/hip_runtime.h>
#include <hip/hip_bf16.h>

// Problem constants
#define BATCH 16
#define CH    32      // depthwise group count
#define CIN   64
#define OUTC  64
#define HH    128     // h after stride-2 stem
#define WW    128

// ---------------------------------------------------------------------------
// Kernel 0: weight prep.
//  - wT  [192][64]: transpose of w_out [64][192]
//  - wTs [32][9][32]: stem weights w_inp [co][ci][tap] -> [ci][tap][co]
// ---------------------------------------------------------------------------
__global__ __launch_bounds__(256) void k_prep_weights(
    const float* __restrict__ w_out, const float* __restrict__ w_inp,
    float* __restrict__ wT, float* __restrict__ wTs) {
  int t = blockIdx.x * 256 + threadIdx.x;
  if (t < OUTC * 3 * CIN) {
    int o = t / (3 * CIN);
    int k = t % (3 * CIN);
    wT[k * OUTC + o] = w_out[t];
  }
  int t2 = t - OUTC * 3 * CIN;
  if (t2 >= 0 && t2 < CH * 9 * CH) {
    // t2 indexes [co][ci][tap] flat (source order)
    int tap = t2 % 9;
    int ci  = (t2 / 9) % CH;
    int co  = t2 / (9 * CH);
    wTs[(ci * 9 + tap) * CH + co] = w_inp[t2];
  }
}

// ---------------------------------------------------------------------------
// Kernel 1: stem = SiLU(conv3x3 stride2 pad1 (mas, w_inp) + b_inp)
// Tile: 4 out rows x 64 out cols; 1024 blocks (4/CU). 256 threads = 4 waves;
// wave g owns co [8g,8g+8); lane tx owns one output column, 4 rows.
// Inputs in parity-split LDS (stride-1 reads, no 4-way conflicts).
// Weights: 6x float4 batched into registers per (ci,ky), then 96 FMAs.
// ---------------------------------------------------------------------------
__global__ __launch_bounds__(256) void k_stem(
    const float* __restrict__ mas, const float* __restrict__ wTs,
    const float* __restrict__ b_inp, float* __restrict__ xbuf) {
  __shared__ float xe[4][9][66];   // even patch cols: xe[ci][r][j] = col 2j (j=0..64)
  __shared__ float xo[4][9][66];   // odd  patch cols: xo[ci][r][j] = col 2j+1 (j=0..63)

  const int bx = blockIdx.x;        // 0..1   (128/64 col tiles)
  const int by = blockIdx.y;        // 0..31  (128/4 row tiles)
  const int b  = blockIdx.z;        // batch
  const int t  = threadIdx.x;
  const int tx = t & 63;
  int gco = __builtin_amdgcn_readfirstlane((t >> 6) << 3);

  const int I0 = by * 4, J0 = bx * 64;
  const int R0 = 2 * I0 - 1, C0 = 2 * J0 - 1;

  float acc[4][8];                  // [row][co]
#pragma unroll
  for (int r = 0; r < 4; ++r)
#pragma unroll
    for (int j = 0; j < 8; ++j) acc[r][j] = 0.f;

  for (int cc = 0; cc < CH; cc += 4) {
    // stage input patch (zero-filled at borders): 4 ci x 9 rows x 129 cols
    for (int idx = t; idx < 4 * 9 * 129; idx += 256) {
      int c  = idx % 129;
      int r  = (idx / 129) % 9;
      int ci = idx / (129 * 9);
      int gr = R0 + r, gc = C0 + c;
      float v = 0.f;
      // gr <= 255 always; check gr>=0 and col bounds
      if (gr >= 0 && gc >= 0 && gc < 256)
        v = mas[((b * CH + cc + ci) * 256 + gr) * 256 + gc];
      if (c & 1) xo[ci][r][c >> 1] = v;
      else       xe[ci][r][c >> 1] = v;
    }
    __syncthreads();

#pragma unroll
    for (int ci = 0; ci < 4; ++ci) {
      const float* wb = wTs + (cc + ci) * 9 * CH + gco;
#pragma unroll
      for (int ky = 0; ky < 3; ++ky) {
        // batched weight loads for the 3 taps of this ky (uniform addresses)
        float4 wA0 = *(const float4*)(wb + (ky * 3 + 0) * CH);
        float4 wA1 = *(const float4*)(wb + (ky * 3 + 0) * CH + 4);
        float4 wB0 = *(const float4*)(wb + (ky * 3 + 1) * CH);
        float4 wB1 = *(const float4*)(wb + (ky * 3 + 1) * CH + 4);
        float4 wC0 = *(const float4*)(wb + (ky * 3 + 2) * CH);
        float4 wC1 = *(const float4*)(wb + (ky * 3 + 2) * CH + 4);
        // stride-1 LDS reads (2 lanes/bank = free)
        float ve0[4], vo[4], ve1[4];
#pragma unroll
        for (int r = 0; r < 4; ++r) {
          ve0[r] = xe[ci][2 * r + ky][tx];
          vo[r]  = xo[ci][2 * r + ky][tx];
          ve1[r] = xe[ci][2 * r + ky][tx + 1];
        }
#pragma unroll
        for (int r = 0; r < 4; ++r) {
          acc[r][0] += ve0[r] * wA0.x;
          acc[r][1] += ve0[r] * wA0.y;
          acc[r][2] += ve0[r] * wA0.z;
          acc[r][3] += ve0[r] * wA0.w;
          acc[r][4] += ve0[r] * wA1.x;
          acc[r][5] += ve0[r] * wA1.y;
          acc[r][6] += ve0[r] * wA1.z;
          acc[r][7] += ve0[r] * wA1.w;
          acc[r][0] += vo[r] * wB0.x;
          acc[r][1] += vo[r] * wB0.y;
          acc[r][2] += vo[r] * wB0.z;
          acc[r][3] += vo[r] * wB0.w;
          acc[r][4] += vo[r] * wB1.x;
          acc[r][5] += vo[r] * wB1.y;
          acc[r][6] += vo[r] * wB1.z;
          acc[r][7] += vo[r] * wB1.w;
          acc[r][0] += ve1[r] * wC0.x;
          acc[r][1] += ve1[r] * wC0.y;
          acc[r][2] += ve1[r] * wC0.z;
          acc[r][3] += ve1[r] * wC0.w;
          acc[r][4] += ve1[r] * wC1.x;
          acc[r][5] += ve1[r] * wC1.y;
          acc[r][6] += ve1[r] * wC1.z;
          acc[r][7] += ve1[r] * wC1.w;
        }
      }
    }
    __syncthreads();
  }

  // epilogue: bias + SiLU + coalesced stores (lanes cover a full row)
#pragma unroll
  for (int j = 0; j < 8; ++j) {
    float bj = b_inp[gco + j];
#pragma unroll
    for (int r = 0; r < 4; ++r) {
      float y = acc[r][j] + bj;
      float s = y / (1.f + __expf(-y));   // SiLU
      xbuf[((b * CH + gco + j) * HH + I0 + r) * WW + J0 + tx] = s;
    }
  }
}

// ---------------------------------------------------------------------------
// Kernel 2: fused deltas + grouped 1x1 gates + concat + out conv (+bias)
// (unchanged)
// ---------------------------------------------------------------------------
__global__ __launch_bounds__(256) void k_fused(
    const float* __restrict__ xbuf, const float* __restrict__ cen,
    const float* __restrict__ w1, const float* __restrict__ w2,
    const float* __restrict__ w3, const float* __restrict__ wT,
    const float* __restrict__ b_out, float* __restrict__ out) {
  __shared__ float xp[8][14][17];      // 8-ch chunk, 14x14 halo patch (pitch 17)
  __shared__ float wg[3][CH][2][8];    // w1,w2,w3
  __shared__ float dchunk[32][64];     // 32 k-rows x 64 pixels
  __shared__ float wchunk[32][64];     // matching wT rows

  const int bx = blockIdx.x;   // 0..15 (col tiles of 8)
  const int by = blockIdx.y;   // 0..15 (row tiles of 8)
  const int b  = blockIdx.z;
  const int t  = threadIdx.x;
  const int I0 = by * 8, J0 = bx * 8;

  // stage gating weights (flat layouts match)
  {
    float* wgf = &wg[0][0][0][0];
    for (int idx = t; idx < 3 * 512; idx += 256) {
      float v;
      if (idx < 512)       v = w1[idx];
      else if (idx < 1024) v = w2[idx - 512];
      else                 v = w3[idx - 1024];
      wgf[idx] = v;
    }
  }

  const int og = t >> 4, pg = t & 15;
  const int o0 = og * 4, p0 = pg * 4;
  float acc[4][4];
#pragma unroll
  for (int i = 0; i < 4; ++i)
#pragma unroll
    for (int j = 0; j < 4; ++j) acc[i][j] = 0.f;

  const int wk = t >> 3;           // wchunk staging: row this thread fills
  const int wo = (t & 7) * 8;      // 8 floats starting here

  // ---- channel chunks: deltas + gates -> dchunk rows, GEMM accumulate ----
  for (int cg = 0; cg < CH; cg += 8) {
    // stage halo patch
    for (int idx = t; idx < 8 * 14 * 14; idx += 256) {
      int cc2 = idx % 14;
      int r   = (idx / 14) % 14;
      int c   = idx / 196;
      int gi = I0 - 3 + r, gj = J0 - 3 + cc2;
      float v = 0.f;
      if (gi >= 0 && gi < HH && gj >= 0 && gj < WW)
        v = xbuf[((b * CH + cg + c) * HH + gi) * WW + gj];
      xp[c][r][cc2] = v;
    }
    // stage wT chunk: local rows 0..15 -> square rows 2cg..2cg+15,
    //                 local rows 16..31 -> dout rows 64+2cg..64+2cg+15
    {
      int gk = (wk < 16) ? (2 * cg + wk) : (64 + 2 * cg + wk - 16);
      float4 a = *(const float4*)(wT + gk * OUTC + wo);
      float4 b4 = *(const float4*)(wT + gk * OUTC + wo + 4);
      *(float4*)(&wchunk[wk][wo]) = a;
      *(float4*)(&wchunk[wk][wo + 4]) = b4;
    }
    __syncthreads();

    // deltas + gates -> dchunk (local rows: sq 2c+{0,1}, dout 16+2c+{0,1})
    for (int task = t; task < 512; task += 256) {
      int c = task >> 6;
      int p = task & 63;
      int py = p >> 3, px = p & 7;
      float xc = xp[c][py + 3][px + 3];
      float d[8];
      d[0] = xc - xp[c][py + 0][px + 0];  // (-3,-3)
      d[1] = xc - xp[c][py + 0][px + 3];  // (-3, 0)
      d[2] = xc - xp[c][py + 0][px + 6];  // (-3, 3)
      d[3] = xc - xp[c][py + 3][px + 6];  // ( 0, 3)
      d[4] = xc - xp[c][py + 6][px + 6];  // ( 3, 3)
      d[5] = xc - xp[c][py + 6][px + 3];  // ( 3, 0)
      d[6] = xc - xp[c][py + 6][px + 0];  // ( 3,-3)
      d[7] = xc - xp[c][py + 3][px + 0];  // ( 0,-3)
      const int C = cg + c;
      float g10 = 0, g11 = 0, g20 = 0, g21 = 0, g30 = 0, g31 = 0;
#pragma unroll
      for (int k = 0; k < 8; ++k) {
        g10 += d[k] * wg[0][C][0][k];
        g11 += d[k] * wg[0][C][1][k];
        g20 += d[k] * wg[1][C][0][k];
        g21 += d[k] * wg[1][C][1][k];
        g30 += d[k] * wg[2][C][0][k];
        g31 += d[k] * wg[2][C][1][k];
      }
      dchunk[2 * c + 0][p]      = g10 * g20;   // square
      dchunk[2 * c + 1][p]      = g11 * g21;
      dchunk[16 + 2 * c + 0][p] = g30;         // dout
      dchunk[16 + 2 * c + 1][p] = g31;
    }
    __syncthreads();

    // GEMM accumulate over this chunk's 32 k-rows
#pragma unroll 4
    for (int k = 0; k < 32; ++k) {
      float4 w4 = *(const float4*)(&wchunk[k][o0]);
      float4 a4 = *(const float4*)(&dchunk[k][p0]);
      acc[0][0] += w4.x * a4.x; acc[0][1] += w4.x * a4.y;
      acc[0][2] += w4.x * a4.z; acc[0][3] += w4.x * a4.w;
      acc[1][0] += w4.y * a4.x; acc[1][1] += w4.y * a4.y;
      acc[1][2] += w4.y * a4.z; acc[1][3] += w4.y * a4.w;
      acc[2][0] += w4.z * a4.x; acc[2][1] += w4.z * a4.y;
      acc[2][2] += w4.z * a4.z; acc[2][3] += w4.z * a4.w;
      acc[3][0] += w4.w * a4.x; acc[3][1] += w4.w * a4.y;
      acc[3][2] += w4.w * a4.z; acc[3][3] += w4.w * a4.w;
    }
    __syncthreads();
  }

  // ---- cen chunks: rows 128..191 of the outs panel ----
  for (int cc = 0; cc < 2; ++cc) {
    {
      int gk = 128 + cc * 32 + wk;
      float4 a = *(const float4*)(wT + gk * OUTC + wo);
      float4 b4 = *(const float4*)(wT + gk * OUTC + wo + 4);
      *(float4*)(&wchunk[wk][wo]) = a;
      *(float4*)(&wchunk[wk][wo + 4]) = b4;
    }
    for (int idx = t; idx < 2048; idx += 256) {
      int k = idx >> 6;
      int p = idx & 63;
      int py = p >> 3, px = p & 7;
      dchunk[k][p] =
          cen[((b * CIN + cc * 32 + k) * HH + I0 + py) * WW + J0 + px];
    }
    __syncthreads();

#pragma unroll 4
    for (int k = 0; k < 32; ++k) {
      float4 w4 = *(const float4*)(&wchunk[k][o0]);
      float4 a4 = *(const float4*)(&dchunk[k][p0]);
      acc[0][0] += w4.x * a4.x; acc[0][1] += w4.x * a4.y;
      acc[0][2] += w4.x * a4.z; acc[0][3] += w4.x * a4.w;
      acc[1][0] += w4.y * a4.x; acc[1][1] += w4.y * a4.y;
      acc[1][2] += w4.y * a4.z; acc[1][3] += w4.y * a4.w;
      acc[2][0] += w4.z * a4.x; acc[2][1] += w4.z * a4.y;
      acc[2][2] += w4.z * a4.z; acc[2][3] += w4.z * a4.w;
      acc[3][0] += w4.w * a4.x; acc[3][1] += w4.w * a4.y;
      acc[3][2] += w4.w * a4.z; acc[3][3] += w4.w * a4.w;
    }
    __syncthreads();
  }

  // epilogue: p0 in {0,4,...,60} -> 4 pixels in one row
  const int py = p0 >> 3, px = p0 & 7;
#pragma unroll
  for (int i = 0; i < 4; ++i) {
    float bo = b_out[o0 + i];
    float4 r;
    r.x = acc[i][0] + bo;
    r.y = acc[i][1] + bo;
    r.z = acc[i][2] + bo;
    r.w = acc[i][3] + bo;
    *(float4*)(&out[((b * OUTC + o0 + i) * HH + I0 + py) * WW + J0 + px]) = r;
  }
}

// ---------------------------------------------------------------------------
extern "C" void kernel_launch(void* const* d_in, const int* in_sizes, int n_in,
                              void* d_out, int out_size, void* d_ws, size_t ws_size,
                              hipStream_t stream) {
  const float* cen   = (const float*)d_in[0];
  const float* mas   = (const float*)d_in[1];
  const float* w_inp = (const float*)d_in[2];
  const float* b_inp = (const float*)d_in[3];
  const float* w1    = (const float*)d_in[4];
  const float* w2    = (const float*)d_in[5];
  const float* w3    = (const float*)d_in[6];
  const float* w_out = (const float*)d_in[7];
  const float* b_out = (const float*)d_in[8];
  float* out = (float*)d_out;

  float* xbuf = (float*)d_ws;                        // 16*32*128*128 fp32 = 33.5 MB
  float* wT   = xbuf + (size_t)BATCH * CH * HH * WW; // 192*64 fp32
  float* wTs  = wT + 192 * OUTC;                     // 32*9*32 fp32

  hipLaunchKernelGGL(k_prep_weights, dim3(84), dim3(256), 0, stream,
                     w_out, w_inp, wT, wTs);
  hipLaunchKernelGGL(k_stem, dim3(2, 32, 16), dim3(256), 0, stream,
                     mas, wTs, b_inp, xbuf);
  hipLaunchKernelGGL(k_fused, dim3(16, 16, 16), dim3(256), 0, stream,
                     xbuf, cen, w1, w2, w3, wT, b_out, out);
}

// Round 5
// 239.545 us; speedup vs baseline: 2.2645x; 1.1924x over previous
//
#include <hip/hip_runtime.h>
#include <hip/hip_bf16.h>

// Problem constants
#define BATCH 16
#define CH    32      // depthwise group count
#define CIN   64
#define OUTC  64
#define HH    128     // h after stride-2 stem
#define WW    128

typedef __attribute__((ext_vector_type(8))) short bf16x8;
typedef __attribute__((ext_vector_type(4))) float f32x4;

__device__ inline unsigned short bf16u(float x) {
  union { __hip_bfloat16 h; unsigned short s; } u;
  u.h = __float2bfloat16(x);
  return u.s;
}

// ---------------------------------------------------------------------------
// Kernel 0: weight prep.
//  - wT    [192][64] fp32: transpose of w_out [64][192]  (for k_fused)
//  - wfrag [9][2][64][8] bf16: stem weights in MFMA A-fragment order:
//      wfrag[tap][ct][lane][e] = bf16(w_inp[co][ci][tap]),
//      co = ct*16 + (lane&15), ci = (lane>>4)*8 + e
// ---------------------------------------------------------------------------
__global__ __launch_bounds__(256) void k_prep_weights(
    const float* __restrict__ w_out, const float* __restrict__ w_inp,
    float* __restrict__ wT, unsigned short* __restrict__ wfrag) {
  int t = blockIdx.x * 256 + threadIdx.x;
  if (t < OUTC * 3 * CIN) {
    int o = t / (3 * CIN);
    int k = t % (3 * CIN);
    wT[k * OUTC + o] = w_out[t];
  }
  int t3 = t - OUTC * 3 * CIN;
  if (t3 >= 0 && t3 < 9 * 2 * 64 * 8) {
    int e    = t3 & 7;
    int lane = (t3 >> 3) & 63;
    int ct   = (t3 >> 9) & 1;
    int tap  = t3 >> 10;
    int co = ct * 16 + (lane & 15);
    int ci = (lane >> 4) * 8 + e;
    wfrag[t3] = bf16u(w_inp[(co * CH + ci) * 9 + tap]);
  }
}

// ---------------------------------------------------------------------------
// Kernel 1: stem via bf16 MFMA.  D[co][px] = sum_{tap,ci} W * x, K-step = tap.
// Block: 2 out rows x 64 out cols, 256 thr = 4 waves; wave w = col-tile of 16.
// LDS: input staged bf16, parity-split (stride-2 conv -> 4 grids), ci-pitch 40
// shorts (80B -> conflict-free-ish reads). Grids (idx units of 40 shorts):
//   REE (even row, even col) base 0,   [2][64]
//   REO (even row, odd  col) base 128, [2][65]
//   ROE (odd  row, even col) base 258, [3][64]
//   ROO (odd  row, odd  col) base 450, [3][65]   total 645
// ---------------------------------------------------------------------------
__global__ __launch_bounds__(256, 3) void k_stem(
    const float* __restrict__ mas, const unsigned short* __restrict__ wfrag,
    const float* __restrict__ b_inp, float* __restrict__ xbuf) {
  __shared__ alignas(16) unsigned short xs[645 * 40];

  const int bx = blockIdx.x;   // 0..1   (col tiles of 64)
  const int by = blockIdx.y;   // 0..63  (row tiles of 2)
  const int b  = blockIdx.z;
  const int t  = threadIdx.x;
  const int lane = t & 63;
  const int w = t >> 6;

  const int I0 = by * 2, J0 = bx * 64;
  const int R0 = 2 * I0 - 1, C0 = 2 * J0 - 1;

  // ---- A-fragments (weights), coalesced, L2-resident ----
  bf16x8 af[9][2];
#pragma unroll
  for (int tap = 0; tap < 9; ++tap)
#pragma unroll
    for (int ct = 0; ct < 2; ++ct)
      af[tap][ct] = ((const bf16x8*)wfrag)[(tap * 2 + ct) * 64 + lane];

  // ---- stage input rows R0..R0+4, cols C0..C0+128 (129), 32 ci, bf16 ----
  if (t < 160) {
    // float4 cells: rows rr=t>>5 (0..4), cols cc = 1+4*(t&31) .. +3
    int rr = t >> 5, c4 = t & 31;
    int ir = R0 + rr;
    int cc0 = 1 + 4 * c4;
    bool vrow = (ir >= 0);
    const float* gp = mas + ((size_t)b * CH * 65536 +
                             (size_t)(vrow ? ir : 0) * 256 + (C0 + cc0));
    int off[4];
#pragma unroll
    for (int j = 0; j < 4; ++j) {
      int cc = cc0 + j;
      int base, idx;
      if (rr & 1) {                       // even input row
        int re = (rr - 1) >> 1;
        if (cc & 1) { base = 0;   idx = re * 64 + ((cc - 1) >> 1); }
        else        { base = 128; idx = re * 65 + (cc >> 1); }
      } else {                            // odd input row
        int ro = rr >> 1;
        if (cc & 1) { base = 258; idx = ro * 64 + ((cc - 1) >> 1); }
        else        { base = 450; idx = ro * 65 + (cc >> 1); }
      }
      off[j] = (base + idx) * 40;
    }
#pragma unroll 4
    for (int ci = 0; ci < 32; ++ci) {
      float4 v = make_float4(0.f, 0.f, 0.f, 0.f);
      if (vrow) v = *(const float4*)(gp + (size_t)ci * 65536);
      xs[off[0] + ci] = bf16u(v.x);
      xs[off[1] + ci] = bf16u(v.y);
      xs[off[2] + ci] = bf16u(v.z);
      xs[off[3] + ci] = bf16u(v.w);
    }
  } else if (t < 165) {
    // scalar cells: cc = 0 (gc = 2*J0-1, odd col), rows rr = t-160
    int rr = t - 160;
    int ir = R0 + rr;
    bool v = (ir >= 0) && (bx > 0);
    int base, idx;
    if (rr & 1) { base = 128; idx = ((rr - 1) >> 1) * 65; }
    else        { base = 450; idx = (rr >> 1) * 65; }
    int off0 = (base + idx) * 40;
    const float* gp = mas + ((size_t)b * CH * 65536 +
                             (size_t)(ir >= 0 ? ir : 0) * 256 +
                             (C0 >= 0 ? C0 : 0));
#pragma unroll 4
    for (int ci = 0; ci < 32; ++ci) {
      float x = v ? gp[(size_t)ci * 65536] : 0.f;
      xs[off0 + ci] = bf16u(x);
    }
  }
  __syncthreads();

  // ---- compute: wave w covers cols [J0+16w, J0+16w+16), rows I0..I0+1 ----
  f32x4 acc[2][2];
#pragma unroll
  for (int il = 0; il < 2; ++il)
#pragma unroll
    for (int ct = 0; ct < 2; ++ct) acc[il][ct] = 0.f;

  const int jl = w * 16 + (lane & 15);   // local output col 0..63
  const int gsh = (lane >> 4) * 8;       // ci-group offset in shorts

#pragma unroll
  for (int ky = 0; ky < 3; ++ky) {
#pragma unroll
    for (int kx = 0; kx < 3; ++kx) {
      const int tap = ky * 3 + kx;
#pragma unroll
      for (int il = 0; il < 2; ++il) {
        int ridx = (ky == 2) ? il + 1 : il;
        int idx;
        if (ky == 1) idx = (kx == 1) ? (0   + ridx * 64 + jl)
                                     : (128 + ridx * 65 + jl + (kx == 2));
        else         idx = (kx == 1) ? (258 + ridx * 64 + jl)
                                     : (450 + ridx * 65 + jl + (kx == 2));
        bf16x8 bfr = *(const bf16x8*)(xs + idx * 40 + gsh);
        acc[il][0] = __builtin_amdgcn_mfma_f32_16x16x32_bf16(
            af[tap][0], bfr, acc[il][0], 0, 0, 0);
        acc[il][1] = __builtin_amdgcn_mfma_f32_16x16x32_bf16(
            af[tap][1], bfr, acc[il][1], 0, 0, 0);
      }
    }
  }

  // ---- epilogue: bias + SiLU, store fp32 ----
  // D layout: col(pixel) = lane&15, row(co within tile) = (lane>>4)*4 + r
  float4 bia[2];
  bia[0] = *(const float4*)(b_inp + (lane >> 4) * 4);
  bia[1] = *(const float4*)(b_inp + 16 + (lane >> 4) * 4);
  const int colg = J0 + jl;
#pragma unroll
  for (int il = 0; il < 2; ++il) {
    int i = I0 + il;
#pragma unroll
    for (int ct = 0; ct < 2; ++ct) {
#pragma unroll
      for (int r = 0; r < 4; ++r) {
        int co = ct * 16 + (lane >> 4) * 4 + r;
        float y = acc[il][ct][r] + ((const float*)&bia[ct])[r];
        float s = y / (1.f + __expf(-y));   // SiLU
        xbuf[((b * CH + co) * HH + i) * WW + colg] = s;
      }
    }
  }
}

// ---------------------------------------------------------------------------
// Kernel 2: fused deltas + grouped 1x1 gates + concat + out conv (+bias)
// (unchanged)
// ---------------------------------------------------------------------------
__global__ __launch_bounds__(256) void k_fused(
    const float* __restrict__ xbuf, const float* __restrict__ cen,
    const float* __restrict__ w1, const float* __restrict__ w2,
    const float* __restrict__ w3, const float* __restrict__ wT,
    const float* __restrict__ b_out, float* __restrict__ out) {
  __shared__ float xp[8][14][17];      // 8-ch chunk, 14x14 halo patch (pitch 17)
  __shared__ float wg[3][CH][2][8];    // w1,w2,w3
  __shared__ float dchunk[32][64];     // 32 k-rows x 64 pixels
  __shared__ float wchunk[32][64];     // matching wT rows

  const int bx = blockIdx.x;   // 0..15 (col tiles of 8)
  const int by = blockIdx.y;   // 0..15 (row tiles of 8)
  const int b  = blockIdx.z;
  const int t  = threadIdx.x;
  const int I0 = by * 8, J0 = bx * 8;

  // stage gating weights (flat layouts match)
  {
    float* wgf = &wg[0][0][0][0];
    for (int idx = t; idx < 3 * 512; idx += 256) {
      float v;
      if (idx < 512)       v = w1[idx];
      else if (idx < 1024) v = w2[idx - 512];
      else                 v = w3[idx - 1024];
      wgf[idx] = v;
    }
  }

  const int og = t >> 4, pg = t & 15;
  const int o0 = og * 4, p0 = pg * 4;
  float acc[4][4];
#pragma unroll
  for (int i = 0; i < 4; ++i)
#pragma unroll
    for (int j = 0; j < 4; ++j) acc[i][j] = 0.f;

  const int wk = t >> 3;           // wchunk staging: row this thread fills
  const int wo = (t & 7) * 8;      // 8 floats starting here

  // ---- channel chunks: deltas + gates -> dchunk rows, GEMM accumulate ----
  for (int cg = 0; cg < CH; cg += 8) {
    // stage halo patch
    for (int idx = t; idx < 8 * 14 * 14; idx += 256) {
      int cc2 = idx % 14;
      int r   = (idx / 14) % 14;
      int c   = idx / 196;
      int gi = I0 - 3 + r, gj = J0 - 3 + cc2;
      float v = 0.f;
      if (gi >= 0 && gi < HH && gj >= 0 && gj < WW)
        v = xbuf[((b * CH + cg + c) * HH + gi) * WW + gj];
      xp[c][r][cc2] = v;
    }
    // stage wT chunk: local rows 0..15 -> square rows 2cg..2cg+15,
    //                 local rows 16..31 -> dout rows 64+2cg..64+2cg+15
    {
      int gk = (wk < 16) ? (2 * cg + wk) : (64 + 2 * cg + wk - 16);
      float4 a = *(const float4*)(wT + gk * OUTC + wo);
      float4 b4 = *(const float4*)(wT + gk * OUTC + wo + 4);
      *(float4*)(&wchunk[wk][wo]) = a;
      *(float4*)(&wchunk[wk][wo + 4]) = b4;
    }
    __syncthreads();

    // deltas + gates -> dchunk (local rows: sq 2c+{0,1}, dout 16+2c+{0,1})
    for (int task = t; task < 512; task += 256) {
      int c = task >> 6;
      int p = task & 63;
      int py = p >> 3, px = p & 7;
      float xc = xp[c][py + 3][px + 3];
      float d[8];
      d[0] = xc - xp[c][py + 0][px + 0];  // (-3,-3)
      d[1] = xc - xp[c][py + 0][px + 3];  // (-3, 0)
      d[2] = xc - xp[c][py + 0][px + 6];  // (-3, 3)
      d[3] = xc - xp[c][py + 3][px + 6];  // ( 0, 3)
      d[4] = xc - xp[c][py + 6][px + 6];  // ( 3, 3)
      d[5] = xc - xp[c][py + 6][px + 3];  // ( 3, 0)
      d[6] = xc - xp[c][py + 6][px + 0];  // ( 3,-3)
      d[7] = xc - xp[c][py + 3][px + 0];  // ( 0,-3)
      const int C = cg + c;
      float g10 = 0, g11 = 0, g20 = 0, g21 = 0, g30 = 0, g31 = 0;
#pragma unroll
      for (int k = 0; k < 8; ++k) {
        g10 += d[k] * wg[0][C][0][k];
        g11 += d[k] * wg[0][C][1][k];
        g20 += d[k] * wg[1][C][0][k];
        g21 += d[k] * wg[1][C][1][k];
        g30 += d[k] * wg[2][C][0][k];
        g31 += d[k] * wg[2][C][1][k];
      }
      dchunk[2 * c + 0][p]      = g10 * g20;   // square
      dchunk[2 * c + 1][p]      = g11 * g21;
      dchunk[16 + 2 * c + 0][p] = g30;         // dout
      dchunk[16 + 2 * c + 1][p] = g31;
    }
    __syncthreads();

    // GEMM accumulate over this chunk's 32 k-rows
#pragma unroll 4
    for (int k = 0; k < 32; ++k) {
      float4 w4 = *(const float4*)(&wchunk[k][o0]);
      float4 a4 = *(const float4*)(&dchunk[k][p0]);
      acc[0][0] += w4.x * a4.x; acc[0][1] += w4.x * a4.y;
      acc[0][2] += w4.x * a4.z; acc[0][3] += w4.x * a4.w;
      acc[1][0] += w4.y * a4.x; acc[1][1] += w4.y * a4.y;
      acc[1][2] += w4.y * a4.z; acc[1][3] += w4.y * a4.w;
      acc[2][0] += w4.z * a4.x; acc[2][1] += w4.z * a4.y;
      acc[2][2] += w4.z * a4.z; acc[2][3] += w4.z * a4.w;
      acc[3][0] += w4.w * a4.x; acc[3][1] += w4.w * a4.y;
      acc[3][2] += w4.w * a4.z; acc[3][3] += w4.w * a4.w;
    }
    __syncthreads();
  }

  // ---- cen chunks: rows 128..191 of the outs panel ----
  for (int cc = 0; cc < 2; ++cc) {
    {
      int gk = 128 + cc * 32 + wk;
      float4 a = *(const float4*)(wT + gk * OUTC + wo);
      float4 b4 = *(const float4*)(wT + gk * OUTC + wo + 4);
      *(float4*)(&wchunk[wk][wo]) = a;
      *(float4*)(&wchunk[wk][wo + 4]) = b4;
    }
    for (int idx = t; idx < 2048; idx += 256) {
      int k = idx >> 6;
      int p = idx & 63;
      int py = p >> 3, px = p & 7;
      dchunk[k][p] =
          cen[((b * CIN + cc * 32 + k) * HH + I0 + py) * WW + J0 + px];
    }
    __syncthreads();

#pragma unroll 4
    for (int k = 0; k < 32; ++k) {
      float4 w4 = *(const float4*)(&wchunk[k][o0]);
      float4 a4 = *(const float4*)(&dchunk[k][p0]);
      acc[0][0] += w4.x * a4.x; acc[0][1] += w4.x * a4.y;
      acc[0][2] += w4.x * a4.z; acc[0][3] += w4.x * a4.w;
      acc[1][0] += w4.y * a4.x; acc[1][1] += w4.y * a4.y;
      acc[1][2] += w4.y * a4.z; acc[1][3] += w4.y * a4.w;
      acc[2][0] += w4.z * a4.x; acc[2][1] += w4.z * a4.y;
      acc[2][2] += w4.z * a4.z; acc[2][3] += w4.z * a4.w;
      acc[3][0] += w4.w * a4.x; acc[3][1] += w4.w * a4.y;
      acc[3][2] += w4.w * a4.z; acc[3][3] += w4.w * a4.w;
    }
    __syncthreads();
  }

  // epilogue: p0 in {0,4,...,60} -> 4 pixels in one row
  const int py = p0 >> 3, px = p0 & 7;
#pragma unroll
  for (int i = 0; i < 4; ++i) {
    float bo = b_out[o0 + i];
    float4 r;
    r.x = acc[i][0] + bo;
    r.y = acc[i][1] + bo;
    r.z = acc[i][2] + bo;
    r.w = acc[i][3] + bo;
    *(float4*)(&out[((b * OUTC + o0 + i) * HH + I0 + py) * WW + J0 + px]) = r;
  }
}

// ---------------------------------------------------------------------------
extern "C" void kernel_launch(void* const* d_in, const int* in_sizes, int n_in,
                              void* d_out, int out_size, void* d_ws, size_t ws_size,
                              hipStream_t stream) {
  const float* cen   = (const float*)d_in[0];
  const float* mas   = (const float*)d_in[1];
  const float* w_inp = (const float*)d_in[2];
  const float* b_inp = (const float*)d_in[3];
  const float* w1    = (const float*)d_in[4];
  const float* w2    = (const float*)d_in[5];
  const float* w3    = (const float*)d_in[6];
  const float* w_out = (const float*)d_in[7];
  const float* b_out = (const float*)d_in[8];
  float* out = (float*)d_out;

  float* xbuf = (float*)d_ws;                        // 16*32*128*128 fp32 = 33.5 MB
  float* wT   = xbuf + (size_t)BATCH * CH * HH * WW; // 192*64 fp32
  unsigned short* wfrag = (unsigned short*)(wT + 192 * OUTC); // 9*2*64*8 bf16

  hipLaunchKernelGGL(k_prep_weights, dim3(84), dim3(256), 0, stream,
                     w_out, w_inp, wT, wfrag);
  hipLaunchKernelGGL(k_stem, dim3(2, 64, 16), dim3(256), 0, stream,
                     mas, wfrag, b_inp, xbuf);
  hipLaunchKernelGGL(k_fused, dim3(16, 16, 16), dim3(256), 0, stream,
                     xbuf, cen, w1, w2, w3, wT, b_out, out);
}

// Round 6
// 216.729 us; speedup vs baseline: 2.5029x; 1.1053x over previous
//
#include <hip/hip_runtime.h>
#include <hip/hip_bf16.h>

// Problem constants
#define BATCH 16
#define CH    32      // depthwise group count
#define CIN   64
#define OUTC  64
#define HH    128     // h after stride-2 stem
#define WW    128

typedef __attribute__((ext_vector_type(8))) short bf16x8;
typedef __attribute__((ext_vector_type(4))) float f32x4;

__device__ inline unsigned short bf16u(float x) {
  union { __hip_bfloat16 h; unsigned short s; } u;
  u.h = __float2bfloat16(x);
  return u.s;
}
__device__ inline unsigned int pack2(float lo, float hi) {
  return (unsigned int)bf16u(lo) | ((unsigned int)bf16u(hi) << 16);
}

// ---------------------------------------------------------------------------
// Kernel 0: weight prep (all bf16 MFMA A-fragments).
//  - wfrag  [9][2][64][8]: stem w_inp -> A-frag order
//      co = ct*16+(lane&15), ci = (lane>>4)*8+e, per tap
//  - wfrag2 [6][4][64][8]: out-conv w_out[o][k] -> A-frag order
//      o = ot*16+(lane&15), k = kt*32+(lane>>4)*8+e
// ---------------------------------------------------------------------------
__global__ __launch_bounds__(256) void k_prep_weights(
    const float* __restrict__ w_out, const float* __restrict__ w_inp,
    unsigned short* __restrict__ wfrag, unsigned short* __restrict__ wfrag2) {
  int t = blockIdx.x * 256 + threadIdx.x;
  if (t < 9 * 2 * 64 * 8) {
    int e    = t & 7;
    int lane = (t >> 3) & 63;
    int ct   = (t >> 9) & 1;
    int tap  = t >> 10;
    int co = ct * 16 + (lane & 15);
    int ci = (lane >> 4) * 8 + e;
    wfrag[t] = bf16u(w_inp[(co * CH + ci) * 9 + tap]);
  }
  int t4 = t - 9 * 2 * 64 * 8;
  if (t4 >= 0 && t4 < 6 * 4 * 64 * 8) {
    int e    = t4 & 7;
    int lane = (t4 >> 3) & 63;
    int ot   = (t4 >> 9) & 3;
    int kt   = t4 >> 11;
    int o = ot * 16 + (lane & 15);
    int k = kt * 32 + (lane >> 4) * 8 + e;
    wfrag2[t4] = bf16u(w_out[o * 3 * CIN + k]);
  }
}

// ---------------------------------------------------------------------------
// Kernel 1: stem via bf16 MFMA (unchanged from round 4).
// ---------------------------------------------------------------------------
__global__ __launch_bounds__(256, 3) void k_stem(
    const float* __restrict__ mas, const unsigned short* __restrict__ wfrag,
    const float* __restrict__ b_inp, float* __restrict__ xbuf) {
  __shared__ alignas(16) unsigned short xs[645 * 40];

  const int bx = blockIdx.x;   // 0..1   (col tiles of 64)
  const int by = blockIdx.y;   // 0..63  (row tiles of 2)
  const int b  = blockIdx.z;
  const int t  = threadIdx.x;
  const int lane = t & 63;
  const int w = t >> 6;

  const int I0 = by * 2, J0 = bx * 64;
  const int R0 = 2 * I0 - 1, C0 = 2 * J0 - 1;

  // ---- A-fragments (weights), coalesced, L2-resident ----
  bf16x8 af[9][2];
#pragma unroll
  for (int tap = 0; tap < 9; ++tap)
#pragma unroll
    for (int ct = 0; ct < 2; ++ct)
      af[tap][ct] = ((const bf16x8*)wfrag)[(tap * 2 + ct) * 64 + lane];

  // ---- stage input rows R0..R0+4, cols C0..C0+128 (129), 32 ci, bf16 ----
  if (t < 160) {
    int rr = t >> 5, c4 = t & 31;
    int ir = R0 + rr;
    int cc0 = 1 + 4 * c4;
    bool vrow = (ir >= 0);
    const float* gp = mas + ((size_t)b * CH * 65536 +
                             (size_t)(vrow ? ir : 0) * 256 + (C0 + cc0));
    int off[4];
#pragma unroll
    for (int j = 0; j < 4; ++j) {
      int cc = cc0 + j;
      int base, idx;
      if (rr & 1) {                       // even input row
        int re = (rr - 1) >> 1;
        if (cc & 1) { base = 0;   idx = re * 64 + ((cc - 1) >> 1); }
        else        { base = 128; idx = re * 65 + (cc >> 1); }
      } else {                            // odd input row
        int ro = rr >> 1;
        if (cc & 1) { base = 258; idx = ro * 64 + ((cc - 1) >> 1); }
        else        { base = 450; idx = ro * 65 + (cc >> 1); }
      }
      off[j] = (base + idx) * 40;
    }
#pragma unroll 4
    for (int ci = 0; ci < 32; ++ci) {
      float4 v = make_float4(0.f, 0.f, 0.f, 0.f);
      if (vrow) v = *(const float4*)(gp + (size_t)ci * 65536);
      xs[off[0] + ci] = bf16u(v.x);
      xs[off[1] + ci] = bf16u(v.y);
      xs[off[2] + ci] = bf16u(v.z);
      xs[off[3] + ci] = bf16u(v.w);
    }
  } else if (t < 165) {
    int rr = t - 160;
    int ir = R0 + rr;
    bool v = (ir >= 0) && (bx > 0);
    int base, idx;
    if (rr & 1) { base = 128; idx = ((rr - 1) >> 1) * 65; }
    else        { base = 450; idx = (rr >> 1) * 65; }
    int off0 = (base + idx) * 40;
    const float* gp = mas + ((size_t)b * CH * 65536 +
                             (size_t)(ir >= 0 ? ir : 0) * 256 +
                             (C0 >= 0 ? C0 : 0));
#pragma unroll 4
    for (int ci = 0; ci < 32; ++ci) {
      float x = v ? gp[(size_t)ci * 65536] : 0.f;
      xs[off0 + ci] = bf16u(x);
    }
  }
  __syncthreads();

  // ---- compute: wave w covers cols [J0+16w, J0+16w+16), rows I0..I0+1 ----
  f32x4 acc[2][2];
#pragma unroll
  for (int il = 0; il < 2; ++il)
#pragma unroll
    for (int ct = 0; ct < 2; ++ct) acc[il][ct] = 0.f;

  const int jl = w * 16 + (lane & 15);   // local output col 0..63
  const int gsh = (lane >> 4) * 8;       // ci-group offset in shorts

#pragma unroll
  for (int ky = 0; ky < 3; ++ky) {
#pragma unroll
    for (int kx = 0; kx < 3; ++kx) {
      const int tap = ky * 3 + kx;
#pragma unroll
      for (int il = 0; il < 2; ++il) {
        int ridx = (ky == 2) ? il + 1 : il;
        int idx;
        if (ky == 1) idx = (kx == 1) ? (0   + ridx * 64 + jl)
                                     : (128 + ridx * 65 + jl + (kx == 2));
        else         idx = (kx == 1) ? (258 + ridx * 64 + jl)
                                     : (450 + ridx * 65 + jl + (kx == 2));
        bf16x8 bfr = *(const bf16x8*)(xs + idx * 40 + gsh);
        acc[il][0] = __builtin_amdgcn_mfma_f32_16x16x32_bf16(
            af[tap][0], bfr, acc[il][0], 0, 0, 0);
        acc[il][1] = __builtin_amdgcn_mfma_f32_16x16x32_bf16(
            af[tap][1], bfr, acc[il][1], 0, 0, 0);
      }
    }
  }

  // ---- epilogue: bias + SiLU, store fp32 ----
  float4 bia[2];
  bia[0] = *(const float4*)(b_inp + (lane >> 4) * 4);
  bia[1] = *(const float4*)(b_inp + 16 + (lane >> 4) * 4);
  const int colg = J0 + jl;
#pragma unroll
  for (int il = 0; il < 2; ++il) {
    int i = I0 + il;
#pragma unroll
    for (int ct = 0; ct < 2; ++ct) {
#pragma unroll
      for (int r = 0; r < 4; ++r) {
        int co = ct * 16 + (lane >> 4) * 4 + r;
        float y = acc[il][ct][r] + ((const float*)&bia[ct])[r];
        float s = y / (1.f + __expf(-y));   // SiLU
        xbuf[((b * CH + co) * HH + i) * WW + colg] = s;
      }
    }
  }
}

// ---------------------------------------------------------------------------
// Kernel 2: fused deltas + gates + concat + out conv via bf16 MFMA.
// 256 thr = 4 waves, 8x8 pixel tile. Phase 1 builds the K=192 panel in bf16,
// K-contiguous: outs_b[p][k], pitch 200 shorts (square k<64, dout 64..127,
// cen 128..191; adjacent k pairs packed as u32 writes). Phase 2: wave w does
// outputs [16w,16w+16) x 64 px: 4 px-tiles x 6 k-tiles = 24 MFMAs.
// ---------------------------------------------------------------------------
__global__ __launch_bounds__(256) void k_fused(
    const float* __restrict__ xbuf, const float* __restrict__ cen,
    const float* __restrict__ w1, const float* __restrict__ w2,
    const float* __restrict__ w3, const unsigned short* __restrict__ wfrag2,
    const float* __restrict__ b_out, float* __restrict__ out) {
  __shared__ float xp[8][14][17];                      // halo patch, 7.6 KB
  __shared__ float wg[3][CH][2][8];                    // 6 KB
  __shared__ alignas(16) unsigned short outs_b[64][200];  // 25.6 KB

  const int bx = blockIdx.x;   // 0..15 (col tiles of 8)
  const int by = blockIdx.y;   // 0..15 (row tiles of 8)
  const int b  = blockIdx.z;
  const int t  = threadIdx.x;
  const int lane = t & 63;
  const int w = t >> 6;
  const int I0 = by * 8, J0 = bx * 8;

  // A-fragments for this wave's o-tile (L2-resident, issue early)
  bf16x8 af2[6];
#pragma unroll
  for (int kt = 0; kt < 6; ++kt)
    af2[kt] = ((const bf16x8*)wfrag2)[(kt * 4 + w) * 64 + lane];

  // stage gating weights (flat layouts match)
  {
    float* wgf = &wg[0][0][0][0];
    for (int idx = t; idx < 3 * 512; idx += 256) {
      float v;
      if (idx < 512)       v = w1[idx];
      else if (idx < 1024) v = w2[idx - 512];
      else                 v = w3[idx - 1024];
      wgf[idx] = v;
    }
  }

  // stage cen -> panel rows k=128..191 (2 channels packed per u32)
  for (int idx = t; idx < 64 * 32; idx += 256) {
    int cc = idx >> 6;          // cen channel pair 0..31
    int p  = idx & 63;
    int py = p >> 3, px = p & 7;
    const float* cp = cen + ((size_t)(b * CIN + 2 * cc) * HH + I0 + py) * WW
                      + J0 + px;
    float v0 = cp[0];
    float v1 = cp[(size_t)HH * WW];
    *(unsigned int*)&outs_b[p][128 + 2 * cc] = pack2(v0, v1);
  }

  // ---- channel chunks: deltas + gates -> panel rows k<128 ----
  for (int cg = 0; cg < CH; cg += 8) {
    for (int idx = t; idx < 8 * 14 * 14; idx += 256) {
      int cc2 = idx % 14;
      int r   = (idx / 14) % 14;
      int c   = idx / 196;
      int gi = I0 - 3 + r, gj = J0 - 3 + cc2;
      float v = 0.f;
      if (gi >= 0 && gi < HH && gj >= 0 && gj < WW)
        v = xbuf[((b * CH + cg + c) * HH + gi) * WW + gj];
      xp[c][r][cc2] = v;
    }
    __syncthreads();

    for (int task = t; task < 512; task += 256) {
      int c = task >> 6;
      int p = task & 63;
      int py = p >> 3, px = p & 7;
      float xc = xp[c][py + 3][px + 3];
      float d[8];
      d[0] = xc - xp[c][py + 0][px + 0];  // (-3,-3)
      d[1] = xc - xp[c][py + 0][px + 3];  // (-3, 0)
      d[2] = xc - xp[c][py + 0][px + 6];  // (-3, 3)
      d[3] = xc - xp[c][py + 3][px + 6];  // ( 0, 3)
      d[4] = xc - xp[c][py + 6][px + 6];  // ( 3, 3)
      d[5] = xc - xp[c][py + 6][px + 3];  // ( 3, 0)
      d[6] = xc - xp[c][py + 6][px + 0];  // ( 3,-3)
      d[7] = xc - xp[c][py + 3][px + 0];  // ( 0,-3)
      const int C = cg + c;
      float g10 = 0, g11 = 0, g20 = 0, g21 = 0, g30 = 0, g31 = 0;
#pragma unroll
      for (int k = 0; k < 8; ++k) {
        g10 += d[k] * wg[0][C][0][k];
        g11 += d[k] * wg[0][C][1][k];
        g20 += d[k] * wg[1][C][0][k];
        g21 += d[k] * wg[1][C][1][k];
        g30 += d[k] * wg[2][C][0][k];
        g31 += d[k] * wg[2][C][1][k];
      }
      *(unsigned int*)&outs_b[p][2 * C]      = pack2(g10 * g20, g11 * g21);
      *(unsigned int*)&outs_b[p][64 + 2 * C] = pack2(g30, g31);
    }
    __syncthreads();
  }

  // ---- Phase 2: MFMA GEMM. Wave w: outputs [16w,16w+16), 64 pixels ----
  f32x4 acc[4];
#pragma unroll
  for (int pt = 0; pt < 4; ++pt) acc[pt] = 0.f;

  const int prow = (lane & 15);
  const int gsh = (lane >> 4) * 8;
#pragma unroll
  for (int pt = 0; pt < 4; ++pt) {
#pragma unroll
    for (int kt = 0; kt < 6; ++kt) {
      bf16x8 bfr = *(const bf16x8*)(&outs_b[pt * 16 + prow][kt * 32 + gsh]);
      acc[pt] = __builtin_amdgcn_mfma_f32_16x16x32_bf16(
          af2[kt], bfr, acc[pt], 0, 0, 0);
    }
  }

  // epilogue: D col = pixel = lane&15 (+16*pt), row = o = 16w+(lane>>4)*4+r
  float4 bo = *(const float4*)(b_out + w * 16 + (lane >> 4) * 4);
#pragma unroll
  for (int pt = 0; pt < 4; ++pt) {
    int p = pt * 16 + prow;
    int py = p >> 3, px = p & 7;
#pragma unroll
    for (int r = 0; r < 4; ++r) {
      int o = w * 16 + (lane >> 4) * 4 + r;
      out[((b * OUTC + o) * HH + I0 + py) * WW + J0 + px] =
          acc[pt][r] + ((const float*)&bo)[r];
    }
  }
}

// ---------------------------------------------------------------------------
extern "C" void kernel_launch(void* const* d_in, const int* in_sizes, int n_in,
                              void* d_out, int out_size, void* d_ws, size_t ws_size,
                              hipStream_t stream) {
  const float* cen   = (const float*)d_in[0];
  const float* mas   = (const float*)d_in[1];
  const float* w_inp = (const float*)d_in[2];
  const float* b_inp = (const float*)d_in[3];
  const float* w1    = (const float*)d_in[4];
  const float* w2    = (const float*)d_in[5];
  const float* w3    = (const float*)d_in[6];
  const float* w_out = (const float*)d_in[7];
  const float* b_out = (const float*)d_in[8];
  float* out = (float*)d_out;

  float* xbuf = (float*)d_ws;                        // 16*32*128*128 fp32 = 33.5 MB
  unsigned short* wfrag  = (unsigned short*)(xbuf + (size_t)BATCH * CH * HH * WW);
  unsigned short* wfrag2 = wfrag + 9 * 2 * 64 * 8;   // 6*4*64*8 bf16

  hipLaunchKernelGGL(k_prep_weights, dim3(84), dim3(256), 0, stream,
                     w_out, w_inp, wfrag, wfrag2);
  hipLaunchKernelGGL(k_stem, dim3(2, 64, 16), dim3(256), 0, stream,
                     mas, wfrag, b_inp, xbuf);
  hipLaunchKernelGGL(k_fused, dim3(16, 16, 16), dim3(256), 0, stream,
                     xbuf, cen, w1, w2, w3, wfrag2, b_out, out);
}

// Round 7
// 178.709 us; speedup vs baseline: 3.0354x; 1.2127x over previous
//
#include <hip/hip_runtime.h>
#include <hip/hip_bf16.h>

// Problem constants
#define BATCH 16
#define CH    32      // depthwise group count
#define CIN   64
#define OUTC  64
#define HH    128     // h after stride-2 stem
#define WW    128
#define HW    (HH * WW)

typedef __attribute__((ext_vector_type(8))) short bf16x8;
typedef __attribute__((ext_vector_type(4))) float f32x4;

__device__ inline unsigned short bf16u(float x) {
  union { __hip_bfloat16 h; unsigned short s; } u;
  u.h = __float2bfloat16(x);
  return u.s;
}
__device__ inline unsigned int pack2(float lo, float hi) {
  return (unsigned int)bf16u(lo) | ((unsigned int)bf16u(hi) << 16);
}
__device__ inline float losf(unsigned u) { return __uint_as_float(u << 16); }
__device__ inline float hisf(unsigned u) { return __uint_as_float(u & 0xffff0000u); }

// ---------------------------------------------------------------------------
// Kernel 0: weight prep (bf16 MFMA A-fragments).
//  - wfrag  [9][2][64][8]: stem w_inp; row co=ct*16+(l&15), k ci=(l>>4)*8+e
//  - wfrag2 [4][4][64][8]: final GEMM K=128 (k<64 sq -> wout col k;
//           k>=64 cen -> wout col 64+k); row o=ot*16+(l&15)
//  - wfrag3 [9][4][64][8]: folded dout conv: W9[tap][o][C];
//           tap=(ty/3)*3+tx/3 over patch offsets {0,3,6}^2, center tap=4
// ---------------------------------------------------------------------------
__global__ __launch_bounds__(256) void k_prep_weights(
    const float* __restrict__ w_out, const float* __restrict__ w_inp,
    const float* __restrict__ w3,
    unsigned short* __restrict__ wfrag, unsigned short* __restrict__ wfrag2,
    unsigned short* __restrict__ wfrag3) {
  int t = blockIdx.x * 256 + threadIdx.x;
  if (t < 9 * 2 * 64 * 8) {
    int e    = t & 7;
    int lane = (t >> 3) & 63;
    int ct   = (t >> 9) & 1;
    int tap  = t >> 10;
    int co = ct * 16 + (lane & 15);
    int ci = (lane >> 4) * 8 + e;
    wfrag[t] = bf16u(w_inp[(co * CH + ci) * 9 + tap]);
  }
  int t2 = t - 9216;
  if (t2 >= 0 && t2 < 4 * 4 * 64 * 8) {
    int e    = t2 & 7;
    int lane = (t2 >> 3) & 63;
    int ot   = (t2 >> 9) & 3;
    int kt   = t2 >> 11;
    int o = ot * 16 + (lane & 15);
    int k = kt * 32 + (lane >> 4) * 8 + e;
    int col = (k < 64) ? k : 64 + k;   // sq block 0..63, cen block 128..191
    wfrag2[t2] = bf16u(w_out[o * 192 + col]);
  }
  int t3 = t - 9216 - 8192;
  if (t3 >= 0 && t3 < 9 * 4 * 64 * 8) {
    int e    = t3 & 7;
    int lane = (t3 >> 3) & 63;
    int ot   = (t3 >> 9) & 3;
    int tap  = t3 >> 11;
    int o = ot * 16 + (lane & 15);
    int C = (lane >> 4) * 8 + e;
    // patch-tap -> OFFSETS index (center tap 4 -> sum of all)
    const int kmap[9] = {0, 1, 2, 7, -1, 3, 6, 5, 4};
    float v = 0.f;
    if (tap == 4) {
      for (int k = 0; k < 8; ++k)
        for (int op = 0; op < 2; ++op)
          v += w_out[o * 192 + 64 + 2 * C + op] * w3[C * 16 + op * 8 + k];
    } else {
      int k = kmap[tap];
      for (int op = 0; op < 2; ++op)
        v -= w_out[o * 192 + 64 + 2 * C + op] * w3[C * 16 + op * 8 + k];
    }
    wfrag3[t3] = bf16u(v);
  }
}

// ---------------------------------------------------------------------------
// Kernel 1: stem via bf16 MFMA (round-4 structure; output now bf16).
// ---------------------------------------------------------------------------
__global__ __launch_bounds__(256, 3) void k_stem(
    const float* __restrict__ mas, const unsigned short* __restrict__ wfrag,
    const float* __restrict__ b_inp, unsigned short* __restrict__ xbuf) {
  __shared__ alignas(16) unsigned short xs[645 * 40];

  const int bx = blockIdx.x;   // 0..1   (col tiles of 64)
  const int by = blockIdx.y;   // 0..63  (row tiles of 2)
  const int b  = blockIdx.z;
  const int t  = threadIdx.x;
  const int lane = t & 63;
  const int w = t >> 6;

  const int I0 = by * 2, J0 = bx * 64;
  const int R0 = 2 * I0 - 1, C0 = 2 * J0 - 1;

  bf16x8 af[9][2];
#pragma unroll
  for (int tap = 0; tap < 9; ++tap)
#pragma unroll
    for (int ct = 0; ct < 2; ++ct)
      af[tap][ct] = ((const bf16x8*)wfrag)[(tap * 2 + ct) * 64 + lane];

  if (t < 160) {
    int rr = t >> 5, c4 = t & 31;
    int ir = R0 + rr;
    int cc0 = 1 + 4 * c4;
    bool vrow = (ir >= 0);
    const float* gp = mas + ((size_t)b * CH * 65536 +
                             (size_t)(vrow ? ir : 0) * 256 + (C0 + cc0));
    int off[4];
#pragma unroll
    for (int j = 0; j < 4; ++j) {
      int cc = cc0 + j;
      int base, idx;
      if (rr & 1) {
        int re = (rr - 1) >> 1;
        if (cc & 1) { base = 0;   idx = re * 64 + ((cc - 1) >> 1); }
        else        { base = 128; idx = re * 65 + (cc >> 1); }
      } else {
        int ro = rr >> 1;
        if (cc & 1) { base = 258; idx = ro * 64 + ((cc - 1) >> 1); }
        else        { base = 450; idx = ro * 65 + (cc >> 1); }
      }
      off[j] = (base + idx) * 40;
    }
#pragma unroll 4
    for (int ci = 0; ci < 32; ++ci) {
      float4 v = make_float4(0.f, 0.f, 0.f, 0.f);
      if (vrow) v = *(const float4*)(gp + (size_t)ci * 65536);
      xs[off[0] + ci] = bf16u(v.x);
      xs[off[1] + ci] = bf16u(v.y);
      xs[off[2] + ci] = bf16u(v.z);
      xs[off[3] + ci] = bf16u(v.w);
    }
  } else if (t < 165) {
    int rr = t - 160;
    int ir = R0 + rr;
    bool v = (ir >= 0) && (bx > 0);
    int base, idx;
    if (rr & 1) { base = 128; idx = ((rr - 1) >> 1) * 65; }
    else        { base = 450; idx = (rr >> 1) * 65; }
    int off0 = (base + idx) * 40;
    const float* gp = mas + ((size_t)b * CH * 65536 +
                             (size_t)(ir >= 0 ? ir : 0) * 256 +
                             (C0 >= 0 ? C0 : 0));
#pragma unroll 4
    for (int ci = 0; ci < 32; ++ci) {
      float x = v ? gp[(size_t)ci * 65536] : 0.f;
      xs[off0 + ci] = bf16u(x);
    }
  }
  __syncthreads();

  f32x4 acc[2][2];
#pragma unroll
  for (int il = 0; il < 2; ++il)
#pragma unroll
    for (int ct = 0; ct < 2; ++ct) acc[il][ct] = 0.f;

  const int jl = w * 16 + (lane & 15);
  const int gsh = (lane >> 4) * 8;

#pragma unroll
  for (int ky = 0; ky < 3; ++ky) {
#pragma unroll
    for (int kx = 0; kx < 3; ++kx) {
      const int tap = ky * 3 + kx;
#pragma unroll
      for (int il = 0; il < 2; ++il) {
        int ridx = (ky == 2) ? il + 1 : il;
        int idx;
        if (ky == 1) idx = (kx == 1) ? (0   + ridx * 64 + jl)
                                     : (128 + ridx * 65 + jl + (kx == 2));
        else         idx = (kx == 1) ? (258 + ridx * 64 + jl)
                                     : (450 + ridx * 65 + jl + (kx == 2));
        bf16x8 bfr = *(const bf16x8*)(xs + idx * 40 + gsh);
        acc[il][0] = __builtin_amdgcn_mfma_f32_16x16x32_bf16(
            af[tap][0], bfr, acc[il][0], 0, 0, 0);
        acc[il][1] = __builtin_amdgcn_mfma_f32_16x16x32_bf16(
            af[tap][1], bfr, acc[il][1], 0, 0, 0);
      }
    }
  }

  float4 bia[2];
  bia[0] = *(const float4*)(b_inp + (lane >> 4) * 4);
  bia[1] = *(const float4*)(b_inp + 16 + (lane >> 4) * 4);
  const int colg = J0 + jl;
#pragma unroll
  for (int il = 0; il < 2; ++il) {
    int i = I0 + il;
#pragma unroll
    for (int ct = 0; ct < 2; ++ct) {
#pragma unroll
      for (int r = 0; r < 4; ++r) {
        int co = ct * 16 + (lane >> 4) * 4 + r;
        float y = acc[il][ct][r] + ((const float*)&bia[ct])[r];
        float s = y / (1.f + __expf(-y));   // SiLU
        xbuf[((b * CH + co) * HH + i) * WW + colg] = bf16u(s);
      }
    }
  }
}

// ---------------------------------------------------------------------------
// Kernel 2 v2: dout folded into a 9-tap dilated conv (MFMA); square path on
// VALU with dual-channel tasks + scalar gate weights; final GEMM K=128 (sq+cen).
// 256 thr = 4 waves, 8x8 px tile; wave w owns output rows [16w,16w+16).
// LDS: xs 14x14x32 bf16 (pitch 40) + panel [64px][136] bf16 = 33 KB.
// ---------------------------------------------------------------------------
__global__ __launch_bounds__(256, 4) void k_fused(
    const unsigned short* __restrict__ xbuf, const float* __restrict__ cen,
    const float* __restrict__ w1, const float* __restrict__ w2,
    const unsigned short* __restrict__ wfrag2,
    const unsigned short* __restrict__ wfrag3,
    const float* __restrict__ b_out, float* __restrict__ out) {
  __shared__ alignas(16) unsigned short xs[196 * 40];
  __shared__ alignas(16) unsigned short panel[64][136];

  const int bx = blockIdx.x;   // 0..15
  const int by = blockIdx.y;   // 0..15
  const int b  = blockIdx.z;
  const int t  = threadIdx.x;
  const int lane = t & 63;
  const int w = t >> 6;
  const int I0 = by * 8, J0 = bx * 8;

  // A-fragments for this wave's o-tile
  bf16x8 af3[9], af2[4];
#pragma unroll
  for (int tap = 0; tap < 9; ++tap)
    af3[tap] = ((const bf16x8*)wfrag3)[(tap * 4 + w) * 64 + lane];
#pragma unroll
  for (int kt = 0; kt < 4; ++kt)
    af2[kt] = ((const bf16x8*)wfrag2)[(kt * 4 + w) * 64 + lane];

  // stage cen -> panel rows k=64..127 (2 ch per u32)
#pragma unroll
  for (int j = 0; j < 8; ++j) {
    int idx = j * 256 + t;
    int cc = idx >> 6, p = idx & 63;
    int py = p >> 3, px = p & 7;
    const float* cp = cen + ((size_t)(b * CIN + 2 * cc) * HH + I0 + py) * WW
                      + J0 + px;
    *(unsigned int*)&panel[p][64 + 2 * cc] = pack2(cp[0], cp[HW]);
  }

  // stage xs: 14x14 patch x 32 ch, bf16 passthrough (xbuf already bf16)
  {
    int row = t >> 4, col = t & 15;
    if (row < 14 && col < 14) {
      int gi = I0 - 3 + row, gj = J0 - 3 + col;
      bool ok = (gi >= 0 && gi < HH && gj >= 0 && gj < WW);
      const unsigned short* gp = xbuf +
          ((size_t)b * CH * HH + (ok ? gi : 0)) * WW + (ok ? gj : 0);
      unsigned short* sp = xs + (row * 14 + col) * 40;
#pragma unroll 8
      for (int ci = 0; ci < 32; ++ci) {
        unsigned short v = gp[(size_t)ci * HW];
        sp[ci] = ok ? v : (unsigned short)0;
      }
    }
  }
  __syncthreads();

  // ---- Phase A: folded-dout 9-tap dilated conv via MFMA ----
  f32x4 acc[4];
#pragma unroll
  for (int pt = 0; pt < 4; ++pt) acc[pt] = 0.f;

  const int prow = lane & 15;
  const int gsh = (lane >> 4) * 8;
#pragma unroll
  for (int pt = 0; pt < 4; ++pt) {
    int p = pt * 16 + prow;
    int ppy = p >> 3, ppx = p & 7;
#pragma unroll
    for (int ty = 0; ty < 3; ++ty)
#pragma unroll
      for (int tx = 0; tx < 3; ++tx) {
        int pos = (ppy + 3 * ty) * 14 + ppx + 3 * tx;
        bf16x8 bfr = *(const bf16x8*)(xs + pos * 40 + gsh);
        acc[pt] = __builtin_amdgcn_mfma_f32_16x16x32_bf16(
            af3[ty * 3 + tx], bfr, acc[pt], 0, 0, 0);
      }
  }

  // ---- Phase B: square gates (VALU), dual-channel tasks ----
  {
    const int py = lane >> 3, px = lane & 7;
    const int posc = (py + 3) * 14 + (px + 3);
    int pos8[8];
    pos8[0] = (py + 0) * 14 + px + 0;   // (-3,-3)
    pos8[1] = (py + 0) * 14 + px + 3;   // (-3, 0)
    pos8[2] = (py + 0) * 14 + px + 6;   // (-3, 3)
    pos8[3] = (py + 3) * 14 + px + 6;   // ( 0, 3)
    pos8[4] = (py + 6) * 14 + px + 6;   // ( 3, 3)
    pos8[5] = (py + 6) * 14 + px + 3;   // ( 3, 0)
    pos8[6] = (py + 6) * 14 + px + 0;   // ( 3,-3)
    pos8[7] = (py + 3) * 14 + px + 0;   // ( 0,-3)

#pragma unroll
    for (int j = 0; j < 4; ++j) {
      int c2 = __builtin_amdgcn_readfirstlane(j * 4 + w);  // 0..15
      const float* w1lo = w1 + (2 * c2) * 16;       // [o'][k], wave-uniform
      const float* w1hi = w1 + (2 * c2 + 1) * 16;
      const float* w2lo = w2 + (2 * c2) * 16;
      const float* w2hi = w2 + (2 * c2 + 1) * 16;
      unsigned uc = *(const unsigned*)(xs + posc * 40 + 2 * c2);
      float clo = losf(uc), chi = hisf(uc);
      float g1l0 = 0, g1l1 = 0, g2l0 = 0, g2l1 = 0;
      float g1h0 = 0, g1h1 = 0, g2h0 = 0, g2h1 = 0;
#pragma unroll
      for (int k = 0; k < 8; ++k) {
        unsigned us = *(const unsigned*)(xs + pos8[k] * 40 + 2 * c2);
        float dlo = clo - losf(us);
        float dhi = chi - hisf(us);
        g1l0 += dlo * w1lo[k];  g1l1 += dlo * w1lo[8 + k];
        g2l0 += dlo * w2lo[k];  g2l1 += dlo * w2lo[8 + k];
        g1h0 += dhi * w1hi[k];  g1h1 += dhi * w1hi[8 + k];
        g2h0 += dhi * w2hi[k];  g2h1 += dhi * w2hi[8 + k];
      }
      uint2 wv;
      wv.x = pack2(g1l0 * g2l0, g1l1 * g2l1);
      wv.y = pack2(g1h0 * g2h0, g1h1 * g2h1);
      *(uint2*)&panel[lane][4 * c2] = wv;   // rows 4c2..4c2+3
    }
  }
  __syncthreads();

  // ---- Phase C: final GEMM K=128 over panel (sq + cen) ----
#pragma unroll
  for (int pt = 0; pt < 4; ++pt) {
#pragma unroll
    for (int kt = 0; kt < 4; ++kt) {
      bf16x8 bfr = *(const bf16x8*)(&panel[pt * 16 + prow][kt * 32 + gsh]);
      acc[pt] = __builtin_amdgcn_mfma_f32_16x16x32_bf16(
          af2[kt], bfr, acc[pt], 0, 0, 0);
    }
  }

  // epilogue: bias + store fp32
  float4 bo = *(const float4*)(b_out + w * 16 + (lane >> 4) * 4);
#pragma unroll
  for (int pt = 0; pt < 4; ++pt) {
    int p = pt * 16 + prow;
    int ppy = p >> 3, ppx = p & 7;
#pragma unroll
    for (int r = 0; r < 4; ++r) {
      int o = w * 16 + (lane >> 4) * 4 + r;
      out[((b * OUTC + o) * HH + I0 + ppy) * WW + J0 + ppx] =
          acc[pt][r] + ((const float*)&bo)[r];
    }
  }
}

// ---------------------------------------------------------------------------
extern "C" void kernel_launch(void* const* d_in, const int* in_sizes, int n_in,
                              void* d_out, int out_size, void* d_ws, size_t ws_size,
                              hipStream_t stream) {
  const float* cen   = (const float*)d_in[0];
  const float* mas   = (const float*)d_in[1];
  const float* w_inp = (const float*)d_in[2];
  const float* b_inp = (const float*)d_in[3];
  const float* w1    = (const float*)d_in[4];
  const float* w2    = (const float*)d_in[5];
  const float* w3    = (const float*)d_in[6];
  const float* w_out = (const float*)d_in[7];
  const float* b_out = (const float*)d_in[8];
  float* out = (float*)d_out;

  unsigned short* xbuf   = (unsigned short*)d_ws;            // bf16, 16.8 MB
  unsigned short* wfrag  = xbuf + (size_t)BATCH * CH * HW;   // 9216
  unsigned short* wfrag2 = wfrag + 9216;                     // 8192
  unsigned short* wfrag3 = wfrag2 + 8192;                    // 18432

  hipLaunchKernelGGL(k_prep_weights, dim3(140), dim3(256), 0, stream,
                     w_out, w_inp, w3, wfrag, wfrag2, wfrag3);
  hipLaunchKernelGGL(k_stem, dim3(2, 64, 16), dim3(256), 0, stream,
                     mas, wfrag, b_inp, xbuf);
  hipLaunchKernelGGL(k_fused, dim3(16, 16, 16), dim3(256), 0, stream,
                     xbuf, cen, w1, w2, wfrag2, wfrag3, b_out, out);
}

// Round 8
// 142.665 us; speedup vs baseline: 3.8023x; 1.2526x over previous
//
#include <hip/hip_runtime.h>
#include <hip/hip_bf16.h>

// Problem constants
#define BATCH 16
#define CH    32      // depthwise group count
#define CIN   64
#define OUTC  64
#define HH    128     // h after stride-2 stem
#define WW    128
#define HW    (HH * WW)
#define MHW   65536   // mas plane 256*256

typedef __attribute__((ext_vector_type(8))) short bf16x8;
typedef __attribute__((ext_vector_type(4))) float f32x4;

__device__ inline unsigned short bf16u(float x) {
  union { __hip_bfloat16 h; unsigned short s; } u;
  u.h = __float2bfloat16(x);
  return u.s;
}
__device__ inline unsigned int pack2(float lo, float hi) {
  return (unsigned int)bf16u(lo) | ((unsigned int)bf16u(hi) << 16);
}
__device__ inline float losf(unsigned u) { return __uint_as_float(u << 16); }
__device__ inline float hisf(unsigned u) { return __uint_as_float(u & 0xffff0000u); }

// ---------------------------------------------------------------------------
// Kernel 0: weight prep (bf16 MFMA A-fragments). Unchanged from round 6.
// ---------------------------------------------------------------------------
__global__ __launch_bounds__(256) void k_prep_weights(
    const float* __restrict__ w_out, const float* __restrict__ w_inp,
    const float* __restrict__ w3,
    unsigned short* __restrict__ wfrag, unsigned short* __restrict__ wfrag2,
    unsigned short* __restrict__ wfrag3) {
  int t = blockIdx.x * 256 + threadIdx.x;
  if (t < 9 * 2 * 64 * 8) {
    int e    = t & 7;
    int lane = (t >> 3) & 63;
    int ct   = (t >> 9) & 1;
    int tap  = t >> 10;
    int co = ct * 16 + (lane & 15);
    int ci = (lane >> 4) * 8 + e;
    wfrag[t] = bf16u(w_inp[(co * CH + ci) * 9 + tap]);
  }
  int t2 = t - 9216;
  if (t2 >= 0 && t2 < 4 * 4 * 64 * 8) {
    int e    = t2 & 7;
    int lane = (t2 >> 3) & 63;
    int ot   = (t2 >> 9) & 3;
    int kt   = t2 >> 11;
    int o = ot * 16 + (lane & 15);
    int k = kt * 32 + (lane >> 4) * 8 + e;
    int col = (k < 64) ? k : 64 + k;   // sq block 0..63, cen block 128..191
    wfrag2[t2] = bf16u(w_out[o * 192 + col]);
  }
  int t3 = t - 9216 - 8192;
  if (t3 >= 0 && t3 < 9 * 4 * 64 * 8) {
    int e    = t3 & 7;
    int lane = (t3 >> 3) & 63;
    int ot   = (t3 >> 9) & 3;
    int tap  = t3 >> 11;
    int o = ot * 16 + (lane & 15);
    int C = (lane >> 4) * 8 + e;
    const int kmap[9] = {0, 1, 2, 7, -1, 3, 6, 5, 4};
    float v = 0.f;
    if (tap == 4) {
      for (int k = 0; k < 8; ++k)
        for (int op = 0; op < 2; ++op)
          v += w_out[o * 192 + 64 + 2 * C + op] * w3[C * 16 + op * 8 + k];
    } else {
      int k = kmap[tap];
      for (int op = 0; op < 2; ++op)
        v -= w_out[o * 192 + 64 + 2 * C + op] * w3[C * 16 + op * 8 + k];
    }
    wfrag3[t3] = bf16u(v);
  }
}

// ---------------------------------------------------------------------------
// Kernel 1 v3: stem via bf16 MFMA. Tile 4 out-rows x 32 out-cols, 4 waves:
// wave w -> ct = w>>1 (co half), ch = w&1 (col half). Input window 9x65x32ci
// staged bf16 into 4 parity grids (all row-stride 33), pixel pitch 36 shorts:
//   BEE=0 (5x33 even-row even-col), BEO=165, BOE=330 (4x33), BOO=462; 594 px.
// Staging writes: packed ci-pair u32, ~2-4-way worst; B-frag reads 2xb64,
// conflict-free (bank stride 18). Output xbuf is channel-interleaved
// [b][y][x][32ch] bf16 -> 8B uint2 stores.
// ---------------------------------------------------------------------------
#define BEE 0
#define BEO 165
#define BOE 330
#define BOO 462
#define SPITCH 36

__global__ __launch_bounds__(256, 3) void k_stem(
    const float* __restrict__ mas, const unsigned short* __restrict__ wfrag,
    const float* __restrict__ b_inp, unsigned short* __restrict__ xbuf) {
  __shared__ alignas(16) unsigned short xs[594 * SPITCH];

  const int bx = blockIdx.x;   // 0..3   (col tiles of 32)
  const int by = blockIdx.y;   // 0..31  (row tiles of 4)
  const int b  = blockIdx.z;
  const int t  = threadIdx.x;
  const int lane = t & 63;
  const int w = t >> 6;
  const int ct = w >> 1, chh = w & 1;

  const int I0 = by * 4, J0 = bx * 32;
  const int R0 = 2 * I0 - 1, C0 = 2 * J0 - 1;

  // A-fragments for this wave's co-tile
  bf16x8 af[9];
#pragma unroll
  for (int tap = 0; tap < 9; ++tap)
    af[tap] = ((const bf16x8*)wfrag)[(tap * 2 + ct) * 64 + lane];

  // ---- staging: 144 main cells (chunk*9+rr; 4 cols each) + 9 col-0 cells ----
  if (t < 144) {
    int chunk = t / 9, rr = t % 9;
    int cc0 = 1 + 4 * chunk;
    int ir = R0 + rr;
    bool vrow = (ir >= 0);
    const float* gp = mas + (size_t)b * CH * MHW +
                      (size_t)(vrow ? ir : 0) * 256 + (C0 + cc0);
    int off[4];
#pragma unroll
    for (int j = 0; j < 4; ++j) {
      int cc = cc0 + j;
      int r2 = rr >> 1;
      int pix;
      if (!(rr & 1))
        pix = (cc & 1) ? BEO + r2 * 33 + ((cc - 1) >> 1)
                       : BEE + r2 * 33 + (cc >> 1);
      else
        pix = (cc & 1) ? BOO + r2 * 33 + ((cc - 1) >> 1)
                       : BOE + r2 * 33 + (cc >> 1);
      off[j] = pix * SPITCH;
    }
#pragma unroll 4
    for (int q = 0; q < 16; ++q) {
      float4 v0 = make_float4(0.f, 0.f, 0.f, 0.f);
      float4 v1 = v0;
      if (vrow) {
        v0 = *(const float4*)(gp + (size_t)(2 * q) * MHW);
        v1 = *(const float4*)(gp + (size_t)(2 * q + 1) * MHW);
      }
      *(unsigned*)&xs[off[0] + 2 * q] = pack2(v0.x, v1.x);
      *(unsigned*)&xs[off[1] + 2 * q] = pack2(v0.y, v1.y);
      *(unsigned*)&xs[off[2] + 2 * q] = pack2(v0.z, v1.z);
      *(unsigned*)&xs[off[3] + 2 * q] = pack2(v0.w, v1.w);
    }
  } else if (t < 153) {
    int rr = t - 144;
    int ir = R0 + rr;
    bool ok = (ir >= 0) && (bx > 0);
    int r2 = rr >> 1;
    int pix = (rr & 1) ? (BOE + r2 * 33) : (BEE + r2 * 33);
    const float* gp = mas + (size_t)b * CH * MHW +
                      (size_t)(ir >= 0 ? ir : 0) * 256 + (C0 >= 0 ? C0 : 0);
    int off0 = pix * SPITCH;
#pragma unroll 4
    for (int q = 0; q < 16; ++q) {
      float a0 = 0.f, a1 = 0.f;
      if (ok) {
        a0 = gp[(size_t)(2 * q) * MHW];
        a1 = gp[(size_t)(2 * q + 1) * MHW];
      }
      *(unsigned*)&xs[off0 + 2 * q] = pack2(a0, a1);
    }
  }
  __syncthreads();

  // ---- compute: wave covers cols [J0+16ch, +16), co [16ct, +16), 4 rows ----
  f32x4 acc[4];
#pragma unroll
  for (int il = 0; il < 4; ++il) acc[il] = 0.f;

  const int jt = chh * 16 + (lane & 15);   // tile col 0..31
  const int gsh = (lane >> 4) * 8;

#pragma unroll
  for (int ky = 0; ky < 3; ++ky) {
#pragma unroll
    for (int kx = 0; kx < 3; ++kx) {
      const int tap = ky * 3 + kx;
#pragma unroll
      for (int il = 0; il < 4; ++il) {
        int pix;
        if (ky == 1) {                       // odd input rows, r2 = il
          pix = (kx == 1) ? (BOO + il * 33 + jt)
                          : (BOE + il * 33 + jt + (kx == 2));
        } else {                             // even rows, r2 = il + (ky==2)
          int r2 = il + (ky >> 1);
          pix = (kx == 1) ? (BEO + r2 * 33 + jt)
                          : (BEE + r2 * 33 + jt + (kx == 2));
        }
        bf16x8 bfr = *(const bf16x8*)(xs + pix * SPITCH + gsh);
        acc[il] = __builtin_amdgcn_mfma_f32_16x16x32_bf16(
            af[tap], bfr, acc[il], 0, 0, 0);
      }
    }
  }

  // ---- epilogue: bias + SiLU, store bf16 channel-interleaved ----
  float4 bia = *(const float4*)(b_inp + ct * 16 + (lane >> 4) * 4);
  const int co0 = ct * 16 + (lane >> 4) * 4;
  const int colg = J0 + jt;
#pragma unroll
  for (int il = 0; il < 4; ++il) {
    int i = I0 + il;
    float y0 = acc[il][0] + bia.x;
    float y1 = acc[il][1] + bia.y;
    float y2 = acc[il][2] + bia.z;
    float y3 = acc[il][3] + bia.w;
    float s0 = y0 / (1.f + __expf(-y0));
    float s1 = y1 / (1.f + __expf(-y1));
    float s2 = y2 / (1.f + __expf(-y2));
    float s3 = y3 / (1.f + __expf(-y3));
    uint2 uv;
    uv.x = pack2(s0, s1);
    uv.y = pack2(s2, s3);
    *(uint2*)(xbuf + ((size_t)(b * HH + i) * WW + colg) * 32 + co0) = uv;
  }
}

// ---------------------------------------------------------------------------
// Kernel 2 v3: fused (folded-dout MFMA + square gates + final GEMM K=128).
// xbuf now channel-interleaved -> halo staging is 4 coalesced uint4 loads +
// 8 conflict-free ds_write_b64 per pixel. xs pitch 36, panel pitch 132
// (bank strides 18 / 66 -> conflict-free reads).
// ---------------------------------------------------------------------------
#define PPITCH 132

__global__ __launch_bounds__(256, 4) void k_fused(
    const unsigned short* __restrict__ xbuf, const float* __restrict__ cen,
    const float* __restrict__ w1, const float* __restrict__ w2,
    const unsigned short* __restrict__ wfrag2,
    const unsigned short* __restrict__ wfrag3,
    const float* __restrict__ b_out, float* __restrict__ out) {
  __shared__ alignas(16) unsigned short xs[196 * 36];      // 14.1 KB
  __shared__ alignas(16) unsigned short panel[64][PPITCH]; // 16.9 KB

  const int bx = blockIdx.x;   // 0..15
  const int by = blockIdx.y;   // 0..15
  const int b  = blockIdx.z;
  const int t  = threadIdx.x;
  const int lane = t & 63;
  const int w = t >> 6;
  const int I0 = by * 8, J0 = bx * 8;

  // A-fragments for this wave's o-tile
  bf16x8 af3[9], af2[4];
#pragma unroll
  for (int tap = 0; tap < 9; ++tap)
    af3[tap] = ((const bf16x8*)wfrag3)[(tap * 4 + w) * 64 + lane];
#pragma unroll
  for (int kt = 0; kt < 4; ++kt)
    af2[kt] = ((const bf16x8*)wfrag2)[(kt * 4 + w) * 64 + lane];

  // stage cen -> panel cols k=64..127 (2 ch per u32)
#pragma unroll
  for (int j = 0; j < 8; ++j) {
    int idx = j * 256 + t;
    int cc = idx >> 6, p = idx & 63;
    int py = p >> 3, px = p & 7;
    const float* cp = cen + ((size_t)(b * CIN + 2 * cc) * HH + I0 + py) * WW
                      + J0 + px;
    *(unsigned int*)&panel[p][64 + 2 * cc] = pack2(cp[0], cp[HW]);
  }

  // stage xs: 14x14 halo x 32 ch from channel-interleaved xbuf
  {
    int row = t >> 4, col = t & 15;
    if (row < 14 && col < 14) {
      int gi = I0 - 3 + row, gj = J0 - 3 + col;
      bool ok = (gi >= 0 && gi < HH && gj >= 0 && gj < WW);
      const unsigned short* gp = xbuf +
          ((size_t)((size_t)b * HH + (ok ? gi : 0)) * WW + (ok ? gj : 0)) * 32;
      unsigned short* sp = xs + (row * 14 + col) * 36;
#pragma unroll
      for (int s = 0; s < 4; ++s) {
        uint4 v = make_uint4(0u, 0u, 0u, 0u);
        if (ok) v = *(const uint4*)(gp + 8 * s);
        *(uint2*)(sp + 8 * s)     = make_uint2(v.x, v.y);
        *(uint2*)(sp + 8 * s + 4) = make_uint2(v.z, v.w);
      }
    }
  }
  __syncthreads();

  // ---- Phase A: folded-dout 9-tap dilated conv via MFMA ----
  f32x4 acc[4];
#pragma unroll
  for (int pt = 0; pt < 4; ++pt) acc[pt] = 0.f;

  const int prow = lane & 15;
  const int gsh = (lane >> 4) * 8;
#pragma unroll
  for (int pt = 0; pt < 4; ++pt) {
    int p = pt * 16 + prow;
    int ppy = p >> 3, ppx = p & 7;
#pragma unroll
    for (int ty = 0; ty < 3; ++ty)
#pragma unroll
      for (int tx = 0; tx < 3; ++tx) {
        int pos = (ppy + 3 * ty) * 14 + ppx + 3 * tx;
        bf16x8 bfr = *(const bf16x8*)(xs + pos * 36 + gsh);
        acc[pt] = __builtin_amdgcn_mfma_f32_16x16x32_bf16(
            af3[ty * 3 + tx], bfr, acc[pt], 0, 0, 0);
      }
  }

  // ---- Phase B: square gates (VALU), dual-channel tasks ----
  {
    const int py = lane >> 3, px = lane & 7;
    const int posc = (py + 3) * 14 + (px + 3);
    int pos8[8];
    pos8[0] = (py + 0) * 14 + px + 0;   // (-3,-3)
    pos8[1] = (py + 0) * 14 + px + 3;   // (-3, 0)
    pos8[2] = (py + 0) * 14 + px + 6;   // (-3, 3)
    pos8[3] = (py + 3) * 14 + px + 6;   // ( 0, 3)
    pos8[4] = (py + 6) * 14 + px + 6;   // ( 3, 3)
    pos8[5] = (py + 6) * 14 + px + 3;   // ( 3, 0)
    pos8[6] = (py + 6) * 14 + px + 0;   // ( 3,-3)
    pos8[7] = (py + 3) * 14 + px + 0;   // ( 0,-3)

#pragma unroll
    for (int j = 0; j < 4; ++j) {
      int c2 = __builtin_amdgcn_readfirstlane(j * 4 + w);  // 0..15
      const float* w1lo = w1 + (2 * c2) * 16;       // wave-uniform (scalar)
      const float* w1hi = w1 + (2 * c2 + 1) * 16;
      const float* w2lo = w2 + (2 * c2) * 16;
      const float* w2hi = w2 + (2 * c2 + 1) * 16;
      unsigned uc = *(const unsigned*)(xs + posc * 36 + 2 * c2);
      float clo = losf(uc), chi = hisf(uc);
      float g1l0 = 0, g1l1 = 0, g2l0 = 0, g2l1 = 0;
      float g1h0 = 0, g1h1 = 0, g2h0 = 0, g2h1 = 0;
#pragma unroll
      for (int k = 0; k < 8; ++k) {
        unsigned us = *(const unsigned*)(xs + pos8[k] * 36 + 2 * c2);
        float dlo = clo - losf(us);
        float dhi = chi - hisf(us);
        g1l0 += dlo * w1lo[k];  g1l1 += dlo * w1lo[8 + k];
        g2l0 += dlo * w2lo[k];  g2l1 += dlo * w2lo[8 + k];
        g1h0 += dhi * w1hi[k];  g1h1 += dhi * w1hi[8 + k];
        g2h0 += dhi * w2hi[k];  g2h1 += dhi * w2hi[8 + k];
      }
      uint2 wv;
      wv.x = pack2(g1l0 * g2l0, g1l1 * g2l1);
      wv.y = pack2(g1h0 * g2h0, g1h1 * g2h1);
      *(uint2*)&panel[lane][4 * c2] = wv;   // sq cols 4c2..4c2+3
    }
  }
  __syncthreads();

  // ---- Phase C: final GEMM K=128 over panel (sq + cen) ----
#pragma unroll
  for (int pt = 0; pt < 4; ++pt) {
#pragma unroll
    for (int kt = 0; kt < 4; ++kt) {
      bf16x8 bfr = *(const bf16x8*)(&panel[pt * 16 + prow][kt * 32 + gsh]);
      acc[pt] = __builtin_amdgcn_mfma_f32_16x16x32_bf16(
          af2[kt], bfr, acc[pt], 0, 0, 0);
    }
  }

  // epilogue: bias + store fp32
  float4 bo = *(const float4*)(b_out + w * 16 + (lane >> 4) * 4);
#pragma unroll
  for (int pt = 0; pt < 4; ++pt) {
    int p = pt * 16 + prow;
    int ppy = p >> 3, ppx = p & 7;
#pragma unroll
    for (int r = 0; r < 4; ++r) {
      int o = w * 16 + (lane >> 4) * 4 + r;
      out[((b * OUTC + o) * HH + I0 + ppy) * WW + J0 + ppx] =
          acc[pt][r] + ((const float*)&bo)[r];
    }
  }
}

// ---------------------------------------------------------------------------
extern "C" void kernel_launch(void* const* d_in, const int* in_sizes, int n_in,
                              void* d_out, int out_size, void* d_ws, size_t ws_size,
                              hipStream_t stream) {
  const float* cen   = (const float*)d_in[0];
  const float* mas   = (const float*)d_in[1];
  const float* w_inp = (const float*)d_in[2];
  const float* b_inp = (const float*)d_in[3];
  const float* w1    = (const float*)d_in[4];
  const float* w2    = (const float*)d_in[5];
  const float* w3    = (const float*)d_in[6];
  const float* w_out = (const float*)d_in[7];
  const float* b_out = (const float*)d_in[8];
  float* out = (float*)d_out;

  unsigned short* xbuf   = (unsigned short*)d_ws;            // bf16, 16.8 MB
  unsigned short* wfrag  = xbuf + (size_t)BATCH * HW * 32;   // 9216
  unsigned short* wfrag2 = wfrag + 9216;                     // 8192
  unsigned short* wfrag3 = wfrag2 + 8192;                    // 18432

  hipLaunchKernelGGL(k_prep_weights, dim3(140), dim3(256), 0, stream,
                     w_out, w_inp, w3, wfrag, wfrag2, wfrag3);
  hipLaunchKernelGGL(k_stem, dim3(4, 32, 16), dim3(256), 0, stream,
                     mas, wfrag, b_inp, xbuf);
  hipLaunchKernelGGL(k_fused, dim3(16, 16, 16), dim3(256), 0, stream,
                     xbuf, cen, w1, w2, wfrag2, wfrag3, b_out, out);
}